// Round 1
// baseline (1863.728 us; speedup 1.0000x reference)
//
#include <hip/hip_runtime.h>
#include <hip/hip_bf16.h>
#include <cstdint>
#include <cstddef>

// Problem constants
#define ROWS   27648       // BS * N
#define BSZ    1024
#define NAGENT 27
#define NA_    33
#define OFF_   6
#define ATK_   27
#define HID_   256
#define HEADS_ 4
#define HD_    16
#define V_     8
#define REL_   5
#define IN_    322
#define FLAT_  32
#define NEGV   (-1e10f)

__device__ __forceinline__ float sigmoidf_(float x) { return 1.f / (1.f + __expf(-x)); }

// ---------------------------------------------------------------------------
// Tiled fp32 GEMM: C = act(A @ B^T + bias [+ C if ACC]) ; A: MxK (lda),
// B: NxK row-major (ldb), C: MxN (ldc). M must be a multiple of 64.
// 64x64 tile, BK=16, 256 threads, 4x4 microtile per thread.
// ---------------------------------------------------------------------------
template <int ACT, int ACC>
__global__ __launch_bounds__(256) void gemm_tiled(
    const float* __restrict__ A, int lda,
    const float* __restrict__ B, int ldb,
    const float* __restrict__ bias,
    float* __restrict__ C, int ldc,
    int M, int N, int K) {
  __shared__ float As[16][65];
  __shared__ float Bs[16][65];
  const int tid  = threadIdx.x;
  const int tx   = tid & 15;        // compute col group
  const int ty   = tid >> 4;        // compute row group
  const int m0   = blockIdx.y * 64;
  const int n0   = blockIdx.x * 64;
  const int kidx = tid & 15;        // load k index
  const int ridx = tid >> 4;        // load row index

  float acc[4][4] = {};

  for (int k0 = 0; k0 < K; k0 += 16) {
    const bool kok = (k0 + kidx) < K;
#pragma unroll
    for (int p = 0; p < 4; ++p) {
      int m = ridx + p * 16;
      As[kidx][m] = kok ? A[(size_t)(m0 + m) * lda + k0 + kidx] : 0.f;
    }
#pragma unroll
    for (int p = 0; p < 4; ++p) {
      int n = ridx + p * 16;
      float v = 0.f;
      if (kok && (n0 + n) < N) v = B[(size_t)(n0 + n) * ldb + k0 + kidx];
      Bs[kidx][n] = v;
    }
    __syncthreads();
#pragma unroll
    for (int kk = 0; kk < 16; ++kk) {
      float a[4], b[4];
#pragma unroll
      for (int p = 0; p < 4; ++p) a[p] = As[kk][ty + p * 16];
#pragma unroll
      for (int p = 0; p < 4; ++p) b[p] = Bs[kk][tx + p * 16];
#pragma unroll
      for (int i = 0; i < 4; ++i)
#pragma unroll
        for (int j = 0; j < 4; ++j) acc[i][j] += a[i] * b[j];
    }
    __syncthreads();
  }

#pragma unroll
  for (int i = 0; i < 4; ++i) {
    int m = m0 + ty + i * 16;
#pragma unroll
    for (int j = 0; j < 4; ++j) {
      int n = n0 + tx + j * 16;
      if (n < N) {
        float v = acc[i][j] + (bias ? bias[n] : 0.f);
        if (ACC) v += C[(size_t)m * ldc + n];
        if (ACT == 1) v = fmaxf(v, 0.f);
        C[(size_t)m * ldc + n] = v;
      }
    }
  }
}

// ---------------------------------------------------------------------------
// Skinny GEMM for N <= 64: one wave per row, lane = output column.
// C[row, n] = A[row,:K] . B[n,:K] + bias[n]
// ---------------------------------------------------------------------------
template <int ACT>
__global__ __launch_bounds__(256) void gemm_skinny(
    const float* __restrict__ A, int lda,
    const float* __restrict__ B, int ldb,
    const float* __restrict__ bias,
    float* __restrict__ C, int ldc, int N, int K) {
  const int wave = threadIdx.x >> 6;
  const int lane = threadIdx.x & 63;
  const int row  = blockIdx.x * 4 + wave;
  if (lane >= N) return;
  const float* a = A + (size_t)row * lda;
  const float* w = B + (size_t)lane * ldb;
  float acc = bias ? bias[lane] : 0.f;
  int k = 0;
  for (; k + 4 <= K; k += 4)
    acc += a[k] * w[k] + a[k + 1] * w[k + 1] + a[k + 2] * w[k + 2] + a[k + 3] * w[k + 3];
  for (; k < K; ++k) acc += a[k] * w[k];
  if (ACT == 1) acc = fmaxf(acc, 0.f);
  C[(size_t)row * ldc + lane] = acc;
}

// ---------------------------------------------------------------------------
// GRU elementwise. GI holds [ir+hr | iz+hz | inn] (biases folded in), HN holds
// hn (bias folded). Writes h to H (the d_out h-region).
// ---------------------------------------------------------------------------
__global__ __launch_bounds__(256) void gru_kernel(
    const float* __restrict__ GI, const float* __restrict__ HN,
    const float* __restrict__ Hin, float* __restrict__ H) {
  int idx = blockIdx.x * 256 + threadIdx.x;   // over ROWS*64 float4 groups
  int row = idx >> 6;
  int c   = (idx & 63) << 2;
  const float4 sr = *(const float4*)(GI + (size_t)row * 768 + c);
  const float4 sz = *(const float4*)(GI + (size_t)row * 768 + 256 + c);
  const float4 sn = *(const float4*)(GI + (size_t)row * 768 + 512 + c);
  const float4 hn = *(const float4*)(HN + (size_t)row * 256 + c);
  const float4 hi = *(const float4*)(Hin + (size_t)row * 256 + c);
  float4 o;
#define GRU1(cp)                                                     \
  {                                                                  \
    float r = sigmoidf_(sr.cp);                                      \
    float z = sigmoidf_(sz.cp);                                      \
    float n = tanhf(sn.cp + r * hn.cp);                              \
    o.cp = (1.f - z) * n + z * hi.cp;                                \
  }
  GRU1(x) GRU1(y) GRU1(z) GRU1(w)
#undef GRU1
  *(float4*)(H + (size_t)row * 256 + c) = o;
}

// ---------------------------------------------------------------------------
// Per-row: softmax over attack logits -> value_source -> sender_values (32).
// One wave per row, 4 rows per block. top1 = 1/sum(exp(v - max)).
// ---------------------------------------------------------------------------
__global__ __launch_bounds__(256) void sv_kernel(
    const float* __restrict__ logits, const float* __restrict__ Wv,
    const float* __restrict__ bv, float* __restrict__ SV) {
  const int wave = threadIdx.x >> 6;
  const int lane = threadIdx.x & 63;
  const int row  = blockIdx.x * 4 + wave;
  __shared__ float vs_s[4][29];

  float v = (lane < 27) ? logits[(size_t)row * 33 + 6 + lane] : -INFINITY;
  float m = v;
#pragma unroll
  for (int off = 32; off; off >>= 1) m = fmaxf(m, __shfl_xor(m, off));
  float e = (lane < 27) ? __expf(v - m) : 0.f;
  float s = e;
#pragma unroll
  for (int off = 32; off; off >>= 1) s += __shfl_xor(s, off);
  if (lane < 27) vs_s[wave][lane] = e / s;
  if (lane == 27) vs_s[wave][27] = 1.f;        // can_attack
  if (lane == 28) vs_s[wave][28] = 1.f / s;    // top1 = max prob
  __syncthreads();
  if (lane < 32) {
    float acc = bv[lane];
    const float* w = Wv + lane * 29;
#pragma unroll
    for (int c = 0; c < 29; ++c) acc += w[c] * vs_s[wave][c];
    SV[(size_t)row * 32 + lane] = acc;
  }
}

// ---------------------------------------------------------------------------
// Attention: one block (128 thr) per (b,i) row. Computes pair scores
// (q . (key_h + Wk_r@rel + bk)), null score, top-4 mask over 28, softmax,
// messages, layernorm(32) -> fusion[:,256:288]. Also copies h row into
// fusion[:,0:256].
// ---------------------------------------------------------------------------
__global__ __launch_bounds__(128) void attn_kernel(
    const float* __restrict__ Q, const float* __restrict__ KH,
    const float* __restrict__ REL, const float* __restrict__ Wk,
    const float* __restrict__ bk, const float* __restrict__ SV,
    const float* __restrict__ null_key, const float* __restrict__ null_value,
    const float* __restrict__ ln_g, const float* __restrict__ ln_b,
    const float* __restrict__ H, float* __restrict__ fusion) {
  const int row = blockIdx.x;           // b*27 + i
  const int b   = row / 27;
  const int i   = row - b * 27;
  const int t   = threadIdx.x;

  __shared__ float q_s[64];
  __shared__ float wkr_s[320];          // Wk[:,256:261], 64x5
  __shared__ float bk_s[64];
  __shared__ float s_s[28 * 4];
  __shared__ float a_s[28 * 4];
  __shared__ float m_s[32];

  // copy h row into fusion[:,0:256]
  for (int c = t; c < 256; c += 128)
    fusion[(size_t)row * 288 + c] = H[(size_t)row * 256 + c];

  if (t < 64) {
    q_s[t]  = Q[(size_t)row * 64 + t];
    bk_s[t] = bk[t];
  }
  for (int idx = t; idx < 320; idx += 128) {
    int a = idx / 5, r = idx - a * 5;
    wkr_s[idx] = Wk[(size_t)a * 261 + 256 + r];
  }
  __syncthreads();

  if (t < 108) {
    const int j = t >> 2, h = t & 3;
    const float* rel = REL + ((size_t)row * 27 + j) * 5;
    const float r0 = rel[0], r1 = rel[1], r2 = rel[2], r3 = rel[3], r4 = rel[4];
    const float* kh = KH + ((size_t)b * 27 + j) * 64 + h * 16;
    float s = 0.f;
#pragma unroll
    for (int d = 0; d < 16; ++d) {
      const int a = h * 16 + d;
      float kr = wkr_s[a * 5] * r0 + wkr_s[a * 5 + 1] * r1 + wkr_s[a * 5 + 2] * r2 +
                 wkr_s[a * 5 + 3] * r3 + wkr_s[a * 5 + 4] * r4;
      s += q_s[a] * (kh[d] + kr + bk_s[a]);
    }
    s *= 0.25f;
    if (j == i) s = NEGV;
    s_s[j * 4 + h] = s;
  } else if (t < 112) {
    const int h = t - 108;
    float s = 0.f;
#pragma unroll
    for (int d = 0; d < 16; ++d) s += q_s[h * 16 + d] * null_key[h * 16 + d];
    s_s[27 * 4 + h] = s * 0.25f;
  }
  __syncthreads();

  if (t < 4) {
    const int h = t;
    float t0 = -INFINITY, t1 = -INFINITY, t2 = -INFINITY, t3 = -INFINITY;
    for (int j = 0; j < 28; ++j) {
      float v = s_s[j * 4 + h];
      if (v > t0)      { t3 = t2; t2 = t1; t1 = t0; t0 = v; }
      else if (v > t1) { t3 = t2; t2 = t1; t1 = v; }
      else if (v > t2) { t3 = t2; t2 = v; }
      else if (v > t3) { t3 = v; }
    }
    const float thr = t3, mx = t0;
    float sum = 0.f;
    for (int j = 0; j < 28; ++j) {
      float v = s_s[j * 4 + h];
      float e = (v >= thr) ? __expf(v - mx) : 0.f;
      a_s[j * 4 + h] = e;
      sum += e;
    }
    const float inv = 1.f / sum;
    for (int j = 0; j < 28; ++j) a_s[j * 4 + h] *= inv;
  }
  __syncthreads();

  if (t < 32) {
    const int h = t >> 3, v = t & 7;
    float acc = a_s[27 * 4 + h] * null_value[h * 8 + v];
    for (int j = 0; j < 27; ++j)
      acc += a_s[j * 4 + h] * SV[((size_t)b * 27 + j) * 32 + t];
    m_s[t] = acc;
  }
  __syncthreads();

  if (t < 32) {
    float mu = 0.f;
#pragma unroll
    for (int k = 0; k < 32; ++k) mu += m_s[k];
    mu *= (1.f / 32.f);
    float var = 0.f;
#pragma unroll
    for (int k = 0; k < 32; ++k) { float d = m_s[k] - mu; var += d * d; }
    var *= (1.f / 32.f);
    float nv = (m_s[t] - mu) * rsqrtf(var + 1e-5f) * ln_g[t] + ln_b[t];
    fusion[(size_t)row * 288 + 256 + t] = nv;
  }
}

// ---------------------------------------------------------------------------
// Final: gate = sigmoid(G1.Wg2 + bg2); delta = D1@Wd2^T + bd2;
// out[:, :6] = base logits; out[:, 6:] = attack_logits + 0.1*gate*delta.
// One wave per row: lanes 0..26 delta, lane 27 gate, lanes 28..33 base copy.
// ---------------------------------------------------------------------------
__global__ __launch_bounds__(256) void final_kernel(
    const float* __restrict__ G1, const float* __restrict__ D1,
    const float* __restrict__ Wg2, const float* __restrict__ bg2,
    const float* __restrict__ Wd2, const float* __restrict__ bd2,
    const float* __restrict__ logits, float* __restrict__ out) {
  const int wave = threadIdx.x >> 6;
  const int lane = threadIdx.x & 63;
  const int row  = blockIdx.x * 4 + wave;
  float acc = 0.f;
  if (lane < 27) {
    const float* a = D1 + (size_t)row * 256;
    const float* w = Wd2 + (size_t)lane * 256;
    for (int k = 0; k < 256; k += 4)
      acc += a[k] * w[k] + a[k + 1] * w[k + 1] + a[k + 2] * w[k + 2] + a[k + 3] * w[k + 3];
    acc += bd2[lane];
  } else if (lane == 27) {
    const float* a = G1 + (size_t)row * 256;
    for (int k = 0; k < 256; k += 4)
      acc += a[k] * Wg2[k] + a[k + 1] * Wg2[k + 1] + a[k + 2] * Wg2[k + 2] + a[k + 3] * Wg2[k + 3];
    acc += bg2[0];
  }
  const float gate = sigmoidf_(__shfl(acc, 27));
  if (lane < 27)
    out[(size_t)row * 33 + 6 + lane] = logits[(size_t)row * 33 + 6 + lane] + 0.1f * gate * acc;
  else if (lane >= 28 && lane < 34)
    out[(size_t)row * 33 + (lane - 28)] = logits[(size_t)row * 33 + (lane - 28)];
}

// ---------------------------------------------------------------------------
extern "C" void kernel_launch(void* const* d_in, const int* in_sizes, int n_in,
                              void* d_out, int out_size, void* d_ws, size_t ws_size,
                              hipStream_t stream) {
  const float* inputs = (const float*)d_in[0];
  const float* hidden = (const float*)d_in[1];
  const float* rel    = (const float*)d_in[2];
  const float* W1  = (const float*)d_in[3];  const float* b1  = (const float*)d_in[4];
  const float* Wih = (const float*)d_in[5];  const float* bih = (const float*)d_in[6];
  const float* Whh = (const float*)d_in[7];  const float* bhh = (const float*)d_in[8];
  const float* Wp1 = (const float*)d_in[9];  const float* bp1 = (const float*)d_in[10];
  const float* Wp2 = (const float*)d_in[11]; const float* bp2 = (const float*)d_in[12];
  const float* Wq  = (const float*)d_in[13]; const float* bq  = (const float*)d_in[14];
  const float* Wk  = (const float*)d_in[15]; const float* bk  = (const float*)d_in[16];
  const float* Wv  = (const float*)d_in[17]; const float* bv  = (const float*)d_in[18];
  const float* ln_g = (const float*)d_in[19]; const float* ln_b = (const float*)d_in[20];
  const float* Wg1 = (const float*)d_in[21]; const float* bg1 = (const float*)d_in[22];
  const float* Wg2 = (const float*)d_in[23]; const float* bg2 = (const float*)d_in[24];
  const float* Wd1 = (const float*)d_in[25]; const float* bd1 = (const float*)d_in[26];
  const float* Wd2 = (const float*)d_in[27]; const float* bd2 = (const float*)d_in[28];
  const float* null_key   = (const float*)d_in[29];
  const float* null_value = (const float*)d_in[30];

  // Workspace layout (floats). Base regions:
  //   X  [0 .. 7077888)              27648x256
  //   GI [7077888 .. 28311552)       27648x768  (ir+hr | iz+hz | inn)
  //   HN [28311552 .. 35389440)      27648x256  (hn)
  // Reuse after GRU:
  //   P1 = X ; D1 = X (after logits) ; fusion = GI base (27648x288)
  //   G1 = GI + 7962624 ; logits/SV/Q/KH carved from HN region.
  float* ws = (float*)d_ws;
  float* X      = ws;
  float* GI     = ws + 7077888;
  float* HN     = ws + 28311552;
  float* P1     = X;
  float* logits = HN;                       // 27648*33 = 912384
  float* SV     = HN + 912384;              // 27648*32 = 884736
  float* Q      = HN + 1797120;             // 27648*64
  float* KH     = HN + 3566592;             // 27648*64
  float* fusion = GI;                       // 27648*288 = 7962624
  float* G1     = GI + 7962624;             // 27648*256
  float* D1     = X;

  float* out = (float*)d_out;
  float* H   = out + (size_t)ROWS * 33;     // h output region doubles as buffer

  dim3 blk(256);

  // 1. X = relu(inputs @ W1^T + b1)
  gemm_tiled<1, 0><<<dim3(4, 432), blk, 0, stream>>>(inputs, 322, W1, 322, b1, X, 256, ROWS, 256, 322);
  // 2. GI = X @ Wih^T + bih
  gemm_tiled<0, 0><<<dim3(12, 432), blk, 0, stream>>>(X, 256, Wih, 256, bih, GI, 768, ROWS, 768, 256);
  // 3a. GI[:, 0:512] += hidden @ Whh[0:512]^T + bhh[0:512]
  gemm_tiled<0, 1><<<dim3(8, 432), blk, 0, stream>>>(hidden, 256, Whh, 256, bhh, GI, 768, ROWS, 512, 256);
  // 3b. HN = hidden @ Whh[512:768]^T + bhh[512:768]
  gemm_tiled<0, 0><<<dim3(4, 432), blk, 0, stream>>>(hidden, 256, Whh + 512 * 256, 256, bhh + 512, HN, 256, ROWS, 256, 256);
  // 4. GRU -> h (written into d_out h-region)
  gru_kernel<<<6912, 256, 0, stream>>>(GI, HN, hidden, H);
  // 5. P1 = relu(h @ Wp1^T + bp1)
  gemm_tiled<1, 0><<<dim3(4, 432), blk, 0, stream>>>(H, 256, Wp1, 256, bp1, P1, 256, ROWS, 256, 256);
  // 6. logits = P1 @ Wp2^T + bp2
  gemm_skinny<0><<<6912, 256, 0, stream>>>(P1, 256, Wp2, 256, bp2, logits, 33, 33, 256);
  // 7. softmax + sender values
  sv_kernel<<<6912, 256, 0, stream>>>(logits, Wv, bv, SV);
  // 8. queries & key_h
  gemm_skinny<0><<<6912, 256, 0, stream>>>(H, 256, Wq, 256, bq, Q, 64, 64, 256);
  gemm_skinny<0><<<6912, 256, 0, stream>>>(H, 256, Wk, 261, nullptr, KH, 64, 64, 256);
  // 9. attention + layernorm + h-copy -> fusion
  attn_kernel<<<ROWS, 128, 0, stream>>>(Q, KH, rel, Wk, bk, SV, null_key, null_value, ln_g, ln_b, H, fusion);
  // 10. G1 = relu(fusion @ Wg1^T + bg1)
  gemm_tiled<1, 0><<<dim3(4, 432), blk, 0, stream>>>(fusion, 288, Wg1, 288, bg1, G1, 256, ROWS, 256, 288);
  // 11. D1 = relu(fusion @ Wd1^T + bd1)
  gemm_tiled<1, 0><<<dim3(4, 432), blk, 0, stream>>>(fusion, 288, Wd1, 288, bd1, D1, 256, ROWS, 256, 288);
  // 12. final gate/delta/fuse + base copy
  final_kernel<<<6912, 256, 0, stream>>>(G1, D1, Wg2, bg2, Wd2, bd2, logits, out);
}

// Round 2
// 1215.896 us; speedup vs baseline: 1.5328x; 1.5328x over previous
//
#include <hip/hip_runtime.h>
#include <hip/hip_bf16.h>
#include <cstdint>
#include <cstddef>

// Problem constants
#define ROWS   27648       // BS * N
#define BSZ    1024
#define NAGENT 27
#define NA_    33
#define OFF_   6
#define ATK_   27
#define HID_   256
#define HEADS_ 4
#define HD_    16
#define V_     8
#define REL_   5
#define IN_    322
#define FLAT_  32
#define NEGV   (-1e10f)

__device__ __forceinline__ float sigmoidf_(float x) { return 1.f / (1.f + __expf(-x)); }

// ---------------------------------------------------------------------------
// Tiled fp32 GEMM: C = act(A @ B^T + bias [+ C if ACC]) ; A: MxK (lda),
// B: NxK row-major (ldb), C: MxN (ldc). M must be a multiple of 64.
// 64x64 tile, BK=16, 256 threads, 4x4 microtile per thread.
// ---------------------------------------------------------------------------
template <int ACT, int ACC>
__global__ __launch_bounds__(256) void gemm_tiled(
    const float* __restrict__ A, int lda,
    const float* __restrict__ B, int ldb,
    const float* __restrict__ bias,
    float* __restrict__ C, int ldc,
    int M, int N, int K) {
  __shared__ float As[16][65];
  __shared__ float Bs[16][65];
  const int tid  = threadIdx.x;
  const int tx   = tid & 15;        // compute col group
  const int ty   = tid >> 4;        // compute row group
  const int m0   = blockIdx.y * 64;
  const int n0   = blockIdx.x * 64;
  const int kidx = tid & 15;        // load k index
  const int ridx = tid >> 4;        // load row index

  float acc[4][4] = {};

  for (int k0 = 0; k0 < K; k0 += 16) {
    const bool kok = (k0 + kidx) < K;
#pragma unroll
    for (int p = 0; p < 4; ++p) {
      int m = ridx + p * 16;
      As[kidx][m] = kok ? A[(size_t)(m0 + m) * lda + k0 + kidx] : 0.f;
    }
#pragma unroll
    for (int p = 0; p < 4; ++p) {
      int n = ridx + p * 16;
      float v = 0.f;
      if (kok && (n0 + n) < N) v = B[(size_t)(n0 + n) * ldb + k0 + kidx];
      Bs[kidx][n] = v;
    }
    __syncthreads();
#pragma unroll
    for (int kk = 0; kk < 16; ++kk) {
      float a[4], b[4];
#pragma unroll
      for (int p = 0; p < 4; ++p) a[p] = As[kk][ty + p * 16];
#pragma unroll
      for (int p = 0; p < 4; ++p) b[p] = Bs[kk][tx + p * 16];
#pragma unroll
      for (int i = 0; i < 4; ++i)
#pragma unroll
        for (int j = 0; j < 4; ++j) acc[i][j] += a[i] * b[j];
    }
    __syncthreads();
  }

#pragma unroll
  for (int i = 0; i < 4; ++i) {
    int m = m0 + ty + i * 16;
#pragma unroll
    for (int j = 0; j < 4; ++j) {
      int n = n0 + tx + j * 16;
      if (n < N) {
        float v = acc[i][j] + (bias ? bias[n] : 0.f);
        if (ACC) v += C[(size_t)m * ldc + n];
        if (ACT == 1) v = fmaxf(v, 0.f);
        C[(size_t)m * ldc + n] = v;
      }
    }
  }
}

// ---------------------------------------------------------------------------
// GRU elementwise. GI holds [ir+hr | iz+hz | inn] (biases folded in), HN holds
// hn (bias folded). Writes h to H (the d_out h-region).
// ---------------------------------------------------------------------------
__global__ __launch_bounds__(256) void gru_kernel(
    const float* __restrict__ GI, const float* __restrict__ HN,
    const float* __restrict__ Hin, float* __restrict__ H) {
  int idx = blockIdx.x * 256 + threadIdx.x;   // over ROWS*64 float4 groups
  int row = idx >> 6;
  int c   = (idx & 63) << 2;
  const float4 sr = *(const float4*)(GI + (size_t)row * 768 + c);
  const float4 sz = *(const float4*)(GI + (size_t)row * 768 + 256 + c);
  const float4 sn = *(const float4*)(GI + (size_t)row * 768 + 512 + c);
  const float4 hn = *(const float4*)(HN + (size_t)row * 256 + c);
  const float4 hi = *(const float4*)(Hin + (size_t)row * 256 + c);
  float4 o;
#define GRU1(cp)                                                     \
  {                                                                  \
    float r = sigmoidf_(sr.cp);                                      \
    float z = sigmoidf_(sz.cp);                                      \
    float n = tanhf(sn.cp + r * hn.cp);                              \
    o.cp = (1.f - z) * n + z * hi.cp;                                \
  }
  GRU1(x) GRU1(y) GRU1(z) GRU1(w)
#undef GRU1
  *(float4*)(H + (size_t)row * 256 + c) = o;
}

// ---------------------------------------------------------------------------
// Per-row: softmax over attack logits -> value_source -> sender_values (32).
// One wave per row, 4 rows per block. top1 = 1/sum(exp(v - max)).
// ---------------------------------------------------------------------------
__global__ __launch_bounds__(256) void sv_kernel(
    const float* __restrict__ logits, const float* __restrict__ Wv,
    const float* __restrict__ bv, float* __restrict__ SV) {
  const int wave = threadIdx.x >> 6;
  const int lane = threadIdx.x & 63;
  const int row  = blockIdx.x * 4 + wave;
  __shared__ float vs_s[4][29];

  float v = (lane < 27) ? logits[(size_t)row * 33 + 6 + lane] : -INFINITY;
  float m = v;
#pragma unroll
  for (int off = 32; off; off >>= 1) m = fmaxf(m, __shfl_xor(m, off));
  float e = (lane < 27) ? __expf(v - m) : 0.f;
  float s = e;
#pragma unroll
  for (int off = 32; off; off >>= 1) s += __shfl_xor(s, off);
  if (lane < 27) vs_s[wave][lane] = e / s;
  if (lane == 27) vs_s[wave][27] = 1.f;        // can_attack
  if (lane == 28) vs_s[wave][28] = 1.f / s;    // top1 = max prob
  __syncthreads();
  if (lane < 32) {
    float acc = bv[lane];
    const float* w = Wv + lane * 29;
#pragma unroll
    for (int c = 0; c < 29; ++c) acc += w[c] * vs_s[wave][c];
    SV[(size_t)row * 32 + lane] = acc;
  }
}

// ---------------------------------------------------------------------------
// Attention: one block (128 thr) per (b,i) row. Computes pair scores
// (q . (key_h + Wk_r@rel + bk)), null score, top-4 mask over 28, softmax,
// messages, layernorm(32) -> fusion[:,256:288]. Also copies h row into
// fusion[:,0:256].
// ---------------------------------------------------------------------------
__global__ __launch_bounds__(128) void attn_kernel(
    const float* __restrict__ Q, const float* __restrict__ KH,
    const float* __restrict__ REL, const float* __restrict__ Wk,
    const float* __restrict__ bk, const float* __restrict__ SV,
    const float* __restrict__ null_key, const float* __restrict__ null_value,
    const float* __restrict__ ln_g, const float* __restrict__ ln_b,
    const float* __restrict__ H, float* __restrict__ fusion) {
  const int row = blockIdx.x;           // b*27 + i
  const int b   = row / 27;
  const int i   = row - b * 27;
  const int t   = threadIdx.x;

  __shared__ float q_s[64];
  __shared__ float wkr_s[320];          // Wk[:,256:261], 64x5
  __shared__ float bk_s[64];
  __shared__ float s_s[28 * 4];
  __shared__ float a_s[28 * 4];
  __shared__ float m_s[32];

  // copy h row into fusion[:,0:256]
  for (int c = t; c < 256; c += 128)
    fusion[(size_t)row * 288 + c] = H[(size_t)row * 256 + c];

  if (t < 64) {
    q_s[t]  = Q[(size_t)row * 64 + t];
    bk_s[t] = bk[t];
  }
  for (int idx = t; idx < 320; idx += 128) {
    int a = idx / 5, r = idx - a * 5;
    wkr_s[idx] = Wk[(size_t)a * 261 + 256 + r];
  }
  __syncthreads();

  if (t < 108) {
    const int j = t >> 2, h = t & 3;
    const float* rel = REL + ((size_t)row * 27 + j) * 5;
    const float r0 = rel[0], r1 = rel[1], r2 = rel[2], r3 = rel[3], r4 = rel[4];
    const float* kh = KH + ((size_t)b * 27 + j) * 64 + h * 16;
    float s = 0.f;
#pragma unroll
    for (int d = 0; d < 16; ++d) {
      const int a = h * 16 + d;
      float kr = wkr_s[a * 5] * r0 + wkr_s[a * 5 + 1] * r1 + wkr_s[a * 5 + 2] * r2 +
                 wkr_s[a * 5 + 3] * r3 + wkr_s[a * 5 + 4] * r4;
      s += q_s[a] * (kh[d] + kr + bk_s[a]);
    }
    s *= 0.25f;
    if (j == i) s = NEGV;
    s_s[j * 4 + h] = s;
  } else if (t < 112) {
    const int h = t - 108;
    float s = 0.f;
#pragma unroll
    for (int d = 0; d < 16; ++d) s += q_s[h * 16 + d] * null_key[h * 16 + d];
    s_s[27 * 4 + h] = s * 0.25f;
  }
  __syncthreads();

  if (t < 4) {
    const int h = t;
    float t0 = -INFINITY, t1 = -INFINITY, t2 = -INFINITY, t3 = -INFINITY;
    for (int j = 0; j < 28; ++j) {
      float v = s_s[j * 4 + h];
      if (v > t0)      { t3 = t2; t2 = t1; t1 = t0; t0 = v; }
      else if (v > t1) { t3 = t2; t2 = t1; t1 = v; }
      else if (v > t2) { t3 = t2; t2 = v; }
      else if (v > t3) { t3 = v; }
    }
    const float thr = t3, mx = t0;
    float sum = 0.f;
    for (int j = 0; j < 28; ++j) {
      float v = s_s[j * 4 + h];
      float e = (v >= thr) ? __expf(v - mx) : 0.f;
      a_s[j * 4 + h] = e;
      sum += e;
    }
    const float inv = 1.f / sum;
    for (int j = 0; j < 28; ++j) a_s[j * 4 + h] *= inv;
  }
  __syncthreads();

  if (t < 32) {
    const int h = t >> 3, v = t & 7;
    float acc = a_s[27 * 4 + h] * null_value[h * 8 + v];
    for (int j = 0; j < 27; ++j)
      acc += a_s[j * 4 + h] * SV[((size_t)b * 27 + j) * 32 + t];
    m_s[t] = acc;
  }
  __syncthreads();

  if (t < 32) {
    float mu = 0.f;
#pragma unroll
    for (int k = 0; k < 32; ++k) mu += m_s[k];
    mu *= (1.f / 32.f);
    float var = 0.f;
#pragma unroll
    for (int k = 0; k < 32; ++k) { float d = m_s[k] - mu; var += d * d; }
    var *= (1.f / 32.f);
    float nv = (m_s[t] - mu) * rsqrtf(var + 1e-5f) * ln_g[t] + ln_b[t];
    fusion[(size_t)row * 288 + 256 + t] = nv;
  }
}

// ---------------------------------------------------------------------------
// Final: gate = sigmoid(G1.Wg2 + bg2); delta = D1@Wd2^T + bd2;
// out[:, :6] = base logits; out[:, 6:] = attack_logits + 0.1*gate*delta.
// Weights staged in LDS once per block (stride-257 => conflict-free lane
// rotation). 432 blocks x 4 waves x 16 rows. Activation rows staged in
// per-wave LDS for broadcast reads.
// ---------------------------------------------------------------------------
__global__ __launch_bounds__(256) void final_kernel(
    const float* __restrict__ G1, const float* __restrict__ D1,
    const float* __restrict__ Wg2, const float* __restrict__ bg2,
    const float* __restrict__ Wd2, const float* __restrict__ bd2,
    const float* __restrict__ logits, float* __restrict__ out) {
  __shared__ float w_s[28 * 257];
  __shared__ float d_row[4][256];
  __shared__ float g_row[4][256];
  const int tid = threadIdx.x;
  for (int idx = tid; idx < 27 * 256; idx += 256) {
    int r = idx >> 8, c = idx & 255;
    w_s[r * 257 + c] = Wd2[idx];
  }
  if (tid < 256) w_s[27 * 257 + tid] = Wg2[tid];
  __syncthreads();

  const int wave = tid >> 6, lane = tid & 63;
  const int wl = (lane < 28) ? lane : 0;
  const float* wr = w_s + wl * 257;

  for (int rr = 0; rr < 16; ++rr) {
    const int row = blockIdx.x * 64 + rr * 4 + wave;
    // stage activation rows (coalesced float4 per lane)
    *(float4*)(&d_row[wave][lane * 4]) = *(const float4*)(D1 + (size_t)row * 256 + lane * 4);
    *(float4*)(&g_row[wave][lane * 4]) = *(const float4*)(G1 + (size_t)row * 256 + lane * 4);
    const float* ar = (lane == 27) ? g_row[wave] : d_row[wave];
    float acc = 0.f;
#pragma unroll 8
    for (int k = 0; k < 256; ++k) acc += ar[k] * wr[k];
    if (lane < 27) acc += bd2[lane];
    else if (lane == 27) acc += bg2[0];
    const float gate = sigmoidf_(__shfl(acc, 27));
    if (lane < 27)
      out[(size_t)row * 33 + 6 + lane] = logits[(size_t)row * 33 + 6 + lane] + 0.1f * gate * acc;
    else if (lane >= 28 && lane < 34)
      out[(size_t)row * 33 + (lane - 28)] = logits[(size_t)row * 33 + (lane - 28)];
  }
}

// ---------------------------------------------------------------------------
extern "C" void kernel_launch(void* const* d_in, const int* in_sizes, int n_in,
                              void* d_out, int out_size, void* d_ws, size_t ws_size,
                              hipStream_t stream) {
  const float* inputs = (const float*)d_in[0];
  const float* hidden = (const float*)d_in[1];
  const float* rel    = (const float*)d_in[2];
  const float* W1  = (const float*)d_in[3];  const float* b1  = (const float*)d_in[4];
  const float* Wih = (const float*)d_in[5];  const float* bih = (const float*)d_in[6];
  const float* Whh = (const float*)d_in[7];  const float* bhh = (const float*)d_in[8];
  const float* Wp1 = (const float*)d_in[9];  const float* bp1 = (const float*)d_in[10];
  const float* Wp2 = (const float*)d_in[11]; const float* bp2 = (const float*)d_in[12];
  const float* Wq  = (const float*)d_in[13]; const float* bq  = (const float*)d_in[14];
  const float* Wk  = (const float*)d_in[15]; const float* bk  = (const float*)d_in[16];
  const float* Wv  = (const float*)d_in[17]; const float* bv  = (const float*)d_in[18];
  const float* ln_g = (const float*)d_in[19]; const float* ln_b = (const float*)d_in[20];
  const float* Wg1 = (const float*)d_in[21]; const float* bg1 = (const float*)d_in[22];
  const float* Wg2 = (const float*)d_in[23]; const float* bg2 = (const float*)d_in[24];
  const float* Wd1 = (const float*)d_in[25]; const float* bd1 = (const float*)d_in[26];
  const float* Wd2 = (const float*)d_in[27]; const float* bd2 = (const float*)d_in[28];
  const float* null_key   = (const float*)d_in[29];
  const float* null_value = (const float*)d_in[30];

  float* ws = (float*)d_ws;
  float* X      = ws;
  float* GI     = ws + 7077888;
  float* HN     = ws + 28311552;
  float* P1     = X;
  float* logits = HN;                       // 27648*33 = 912384
  float* SV     = HN + 912384;              // 27648*32 = 884736
  float* Q      = HN + 1797120;             // 27648*64
  float* KH     = HN + 3566592;             // 27648*64
  float* fusion = GI;                       // 27648*288 = 7962624
  float* G1     = GI + 7962624;             // 27648*256
  float* D1     = X;

  float* out = (float*)d_out;
  float* H   = out + (size_t)ROWS * 33;     // h output region doubles as buffer

  dim3 blk(256);

  // 1. X = relu(inputs @ W1^T + b1)
  gemm_tiled<1, 0><<<dim3(4, 432), blk, 0, stream>>>(inputs, 322, W1, 322, b1, X, 256, ROWS, 256, 322);
  // 2. GI = X @ Wih^T + bih
  gemm_tiled<0, 0><<<dim3(12, 432), blk, 0, stream>>>(X, 256, Wih, 256, bih, GI, 768, ROWS, 768, 256);
  // 3a. GI[:, 0:512] += hidden @ Whh[0:512]^T + bhh[0:512]
  gemm_tiled<0, 1><<<dim3(8, 432), blk, 0, stream>>>(hidden, 256, Whh, 256, bhh, GI, 768, ROWS, 512, 256);
  // 3b. HN = hidden @ Whh[512:768]^T + bhh[512:768]
  gemm_tiled<0, 0><<<dim3(4, 432), blk, 0, stream>>>(hidden, 256, Whh + 512 * 256, 256, bhh + 512, HN, 256, ROWS, 256, 256);
  // 4. GRU -> h (written into d_out h-region)
  gru_kernel<<<6912, 256, 0, stream>>>(GI, HN, hidden, H);
  // 5. P1 = relu(h @ Wp1^T + bp1)
  gemm_tiled<1, 0><<<dim3(4, 432), blk, 0, stream>>>(H, 256, Wp1, 256, bp1, P1, 256, ROWS, 256, 256);
  // 6. logits = P1 @ Wp2^T + bp2  (tiled; was skinny @285us)
  gemm_tiled<0, 0><<<dim3(1, 432), blk, 0, stream>>>(P1, 256, Wp2, 256, bp2, logits, 33, ROWS, 33, 256);
  // 7. softmax + sender values
  sv_kernel<<<6912, 256, 0, stream>>>(logits, Wv, bv, SV);
  // 8. queries & key_h (tiled; were skinny @285us each)
  gemm_tiled<0, 0><<<dim3(1, 432), blk, 0, stream>>>(H, 256, Wq, 256, bq, Q, 64, ROWS, 64, 256);
  gemm_tiled<0, 0><<<dim3(1, 432), blk, 0, stream>>>(H, 256, Wk, 261, nullptr, KH, 64, ROWS, 64, 256);
  // 9. attention + layernorm + h-copy -> fusion
  attn_kernel<<<ROWS, 128, 0, stream>>>(Q, KH, rel, Wk, bk, SV, null_key, null_value, ln_g, ln_b, H, fusion);
  // 10. G1 = relu(fusion @ Wg1^T + bg1)
  gemm_tiled<1, 0><<<dim3(4, 432), blk, 0, stream>>>(fusion, 288, Wg1, 288, bg1, G1, 256, ROWS, 256, 288);
  // 11. D1 = relu(fusion @ Wd1^T + bd1)
  gemm_tiled<1, 0><<<dim3(4, 432), blk, 0, stream>>>(fusion, 288, Wd1, 288, bd1, D1, 256, ROWS, 256, 288);
  // 12. final gate/delta/fuse + base copy
  final_kernel<<<432, 256, 0, stream>>>(G1, D1, Wg2, bg2, Wd2, bd2, logits, out);
}

// Round 3
// 493.229 us; speedup vs baseline: 3.7786x; 2.4652x over previous
//
#include <hip/hip_runtime.h>
#include <cstdint>
#include <cstddef>

#define ROWS 27648
#define NEGV (-1e10f)

typedef __attribute__((ext_vector_type(8))) short bf16x8;
typedef __attribute__((ext_vector_type(4))) short short4v;
typedef __attribute__((ext_vector_type(4))) float f32x4;
typedef __attribute__((ext_vector_type(4))) unsigned u32x4;

__device__ __forceinline__ float sigmoidf_(float x) { return 1.f / (1.f + __expf(-x)); }
__device__ __forceinline__ float bf2f(short s) {
  union { float f; unsigned u; } x; x.u = ((unsigned)(unsigned short)s) << 16; return x.f;
}
__device__ __forceinline__ short f2bf(float f) {   // RNE
  union { float f; unsigned u; } x; x.f = f;
  unsigned r = (x.u + 0x7fffu + ((x.u >> 16) & 1u)) >> 16;
  return (short)r;
}

// ---------------------------------------------------------------------------
// bf16 MFMA GEMM: C = act(A @ B^T + bias); A: Mx(lda) bf16, B: Npad x ldb bf16
// (rows padded to >= grid.x*128, zero-filled), C fp32 or bf16, cols < nstore
// stored. 128x128 tile, BK=32, 256 thr, 4 waves each 64x64 via 4x4 MFMAs.
// global_load_lds width=16 staging; LDS layout [row][32k] contiguous (required
// by wave-uniform-base + lane*16 DMA semantics). K, lda, ldb: mult of 32/16/16.
// ---------------------------------------------------------------------------
#define GLDS(gp, lp) __builtin_amdgcn_global_load_lds( \
  (const __attribute__((address_space(1))) void*)(gp), \
  (__attribute__((address_space(3))) void*)(lp), 16, 0, 0)

template <int ACT, int BF16OUT>
__global__ __launch_bounds__(256) void gemm_mfma(
    const short* __restrict__ A, int lda,
    const short* __restrict__ B, int ldb,
    const float* __restrict__ bias,
    void* __restrict__ Cv, int ldc, int nstore, int K) {
  __shared__ short As[128 * 32];
  __shared__ short Bs[128 * 32];
  const int tid = threadIdx.x;
  const int wave = tid >> 6, lane = tid & 63;
  const int m0 = blockIdx.y * 128, n0 = blockIdx.x * 128;
  // staging: wave stages rows [wave*32, wave*32+32) in two 16-row halves;
  // lane -> row lane/4, 16B chunk lane%4 (matches lds base + lane*16).
  const int srow = lane >> 2, scol = (lane & 3) * 8;
  const int sr0 = wave * 32;
  // compute: wave -> 64x64 quadrant
  const int wm = (wave >> 1) * 64, wn = (wave & 1) * 64;
  const int fr = lane & 15, fk = (lane >> 4) * 8;

  f32x4 acc[4][4] = {};

  const short* pA0 = A + (size_t)(m0 + sr0 + srow) * lda + scol;
  const short* pA1 = pA0 + 16 * lda;
  const short* pB0 = B + (size_t)(n0 + sr0 + srow) * ldb + scol;
  const short* pB1 = pB0 + 16 * ldb;
  short* lA0 = &As[sr0 * 32];
  short* lA1 = &As[(sr0 + 16) * 32];
  short* lB0 = &Bs[sr0 * 32];
  short* lB1 = &Bs[(sr0 + 16) * 32];

  for (int k0 = 0; k0 < K; k0 += 32) {
    GLDS(pA0 + k0, lA0);
    GLDS(pA1 + k0, lA1);
    GLDS(pB0 + k0, lB0);
    GLDS(pB1 + k0, lB1);
    __syncthreads();
    bf16x8 af[4], bfr[4];
#pragma unroll
    for (int t = 0; t < 4; ++t) {
      af[t]  = *(const bf16x8*)&As[(wm + t * 16 + fr) * 32 + fk];
      bfr[t] = *(const bf16x8*)&Bs[(wn + t * 16 + fr) * 32 + fk];
    }
#pragma unroll
    for (int i = 0; i < 4; ++i)
#pragma unroll
      for (int j = 0; j < 4; ++j)
        acc[i][j] = __builtin_amdgcn_mfma_f32_16x16x32_bf16(af[i], bfr[j], acc[i][j], 0, 0, 0);
    __syncthreads();
  }

  // C/D layout: col = lane&15 (N side), row = (lane>>4)*4 + reg (M side)
  const int rbase = m0 + wm + (lane >> 4) * 4;
#pragma unroll
  for (int j = 0; j < 4; ++j) {
    const int col = n0 + wn + j * 16 + fr;
    if (col >= nstore) continue;
    const float bv = bias ? bias[col] : 0.f;
#pragma unroll
    for (int i = 0; i < 4; ++i)
#pragma unroll
      for (int r = 0; r < 4; ++r) {
        const int row = rbase + i * 16 + r;
        float v = acc[i][j][r] + bv;
        if (ACT) v = fmaxf(v, 0.f);
        if (BF16OUT) ((short*)Cv)[(size_t)row * ldc + col] = f2bf(v);
        else         ((float*)Cv)[(size_t)row * ldc + col] = v;
      }
  }
}

// ---------------------------------------------------------------------------
// Activation conversion: inputs (27648x322 f32) -> padded bf16 27648x352;
// hidden -> bf16.
// ---------------------------------------------------------------------------
__global__ __launch_bounds__(256) void conv_acts(
    const float* __restrict__ inputs, const float* __restrict__ hidden,
    short* __restrict__ xin, short* __restrict__ hid) {
  const int NX = ROWS * 352;
  int idx = blockIdx.x * 256 + threadIdx.x;
  if (idx < NX) {
    int row = idx / 352, c = idx - row * 352;
    xin[idx] = (c < 322) ? f2bf(inputs[row * 322 + c]) : (short)0;
  } else {
    int j = idx - NX;
    if (j < ROWS * 256) hid[j] = f2bf(hidden[j]);
  }
}

// ---------------------------------------------------------------------------
// Weight conversion / packing into padded bf16 buffers + combined biases.
// ---------------------------------------------------------------------------
__global__ __launch_bounds__(256) void conv_w(
    const float* __restrict__ W1, const float* __restrict__ Wih,
    const float* __restrict__ Whh, const float* __restrict__ Wp1,
    const float* __restrict__ Wp2, const float* __restrict__ Wq,
    const float* __restrict__ Wk, const float* __restrict__ Wg1,
    const float* __restrict__ Wd1, const float* __restrict__ bq,
    const float* __restrict__ bg1, const float* __restrict__ bd1,
    short* __restrict__ w1w, short* __restrict__ wihw, short* __restrict__ whhw,
    short* __restrict__ wp1w, short* __restrict__ wp2w, short* __restrict__ wqkw,
    short* __restrict__ wgdw, float* __restrict__ bqk, float* __restrict__ bgd) {
  int idx = blockIdx.x * 256 + threadIdx.x;
  if (idx < 90112) {            // W1: 256x352 padded from 256x322
    int r = idx / 352, c = idx - r * 352;
    w1w[idx] = (c < 322) ? f2bf(W1[r * 322 + c]) : (short)0;
    return;
  }
  idx -= 90112;
  if (idx < 196608) { wihw[idx] = f2bf(Wih[idx]); return; }
  idx -= 196608;
  if (idx < 196608) { whhw[idx] = f2bf(Whh[idx]); return; }
  idx -= 196608;
  if (idx < 65536) { wp1w[idx] = f2bf(Wp1[idx]); return; }
  idx -= 65536;
  if (idx < 32768) {            // Wp2: 128x256, rows >=33 zero
    wp2w[idx] = (idx < 33 * 256) ? f2bf(Wp2[idx]) : (short)0;
    return;
  }
  idx -= 32768;
  if (idx < 32768) {            // [Wq ; Wk[:, :256]] : 128x256
    int r = idx >> 8, c = idx & 255;
    wqkw[idx] = (r < 64) ? f2bf(Wq[idx]) : f2bf(Wk[(size_t)(r - 64) * 261 + c]);
    return;
  }
  idx -= 32768;
  if (idx < 147456) {           // [Wg1 ; Wd1] : 512x288
    wgdw[idx] = (idx < 73728) ? f2bf(Wg1[idx]) : f2bf(Wd1[idx - 73728]);
    return;
  }
  idx -= 147456;
  if (idx < 128) { bqk[idx] = (idx < 64) ? bq[idx] : 0.f; return; }
  idx -= 128;
  if (idx < 512) { bgd[idx] = (idx < 256) ? bg1[idx] : bd1[idx - 256]; return; }
}

// ---------------------------------------------------------------------------
// GRU elementwise: GI/GH bf16 (biases folded), hidden f32. Writes H f32
// (d_out h region) and h as bf16 into fusion[:, 0:256] (ld 288).
// ---------------------------------------------------------------------------
__global__ __launch_bounds__(256) void gru_kernel(
    const short* __restrict__ GI, const short* __restrict__ GH,
    const float* __restrict__ Hin, float* __restrict__ H,
    short* __restrict__ FUS) {
  int idx = blockIdx.x * 256 + threadIdx.x;  // over ROWS*64 groups of 4
  int row = idx >> 6;
  int c = (idx & 63) * 4;
  const short4v gr = *(const short4v*)(GI + (size_t)row * 768 + c);
  const short4v gz = *(const short4v*)(GI + (size_t)row * 768 + 256 + c);
  const short4v gn = *(const short4v*)(GI + (size_t)row * 768 + 512 + c);
  const short4v hr = *(const short4v*)(GH + (size_t)row * 768 + c);
  const short4v hz = *(const short4v*)(GH + (size_t)row * 768 + 256 + c);
  const short4v hn = *(const short4v*)(GH + (size_t)row * 768 + 512 + c);
  const f32x4 hi = *(const f32x4*)(Hin + (size_t)row * 256 + c);
  f32x4 o;
  short4v ob;
#pragma unroll
  for (int p = 0; p < 4; ++p) {
    float r = sigmoidf_(bf2f(gr[p]) + bf2f(hr[p]));
    float z = sigmoidf_(bf2f(gz[p]) + bf2f(hz[p]));
    float n = tanhf(bf2f(gn[p]) + r * bf2f(hn[p]));
    float h = (1.f - z) * n + z * hi[p];
    o[p] = h;
    ob[p] = f2bf(h);
  }
  *(f32x4*)(H + (size_t)row * 256 + c) = o;
  *(short4v*)(FUS + (size_t)row * 288 + c) = ob;
}

// ---------------------------------------------------------------------------
// Per-row softmax over attack logits -> value_source -> sender_values (32).
// ---------------------------------------------------------------------------
__global__ __launch_bounds__(256) void sv_kernel(
    const float* __restrict__ logits, const float* __restrict__ Wv,
    const float* __restrict__ bv, float* __restrict__ SV) {
  const int wave = threadIdx.x >> 6;
  const int lane = threadIdx.x & 63;
  const int row = blockIdx.x * 4 + wave;
  __shared__ float vs_s[4][29];
  float v = (lane < 27) ? logits[(size_t)row * 33 + 6 + lane] : -INFINITY;
  float m = v;
#pragma unroll
  for (int off = 32; off; off >>= 1) m = fmaxf(m, __shfl_xor(m, off));
  float e = (lane < 27) ? __expf(v - m) : 0.f;
  float s = e;
#pragma unroll
  for (int off = 32; off; off >>= 1) s += __shfl_xor(s, off);
  if (lane < 27) vs_s[wave][lane] = e / s;
  if (lane == 27) vs_s[wave][27] = 1.f;
  if (lane == 28) vs_s[wave][28] = 1.f / s;   // top1 = max prob
  __syncthreads();
  if (lane < 32) {
    float acc = bv[lane];
    const float* w = Wv + lane * 29;
#pragma unroll
    for (int c = 0; c < 29; ++c) acc += w[c] * vs_s[wave][c];
    SV[(size_t)row * 32 + lane] = acc;
  }
}

// ---------------------------------------------------------------------------
// Attention per (b,i): scores -> top4 mask -> softmax -> messages -> LN(32)
// -> fusion[:, 256:288] bf16. Q/KH packed in QK (fp32, ld 128: q=0:64, kh=64:128).
// ---------------------------------------------------------------------------
__global__ __launch_bounds__(128) void attn_kernel(
    const float* __restrict__ QK, const float* __restrict__ rel,
    const float* __restrict__ Wk, const float* __restrict__ bk,
    const float* __restrict__ SV, const float* __restrict__ null_key,
    const float* __restrict__ null_value, const float* __restrict__ ln_g,
    const float* __restrict__ ln_b, short* __restrict__ FUS) {
  const int row = blockIdx.x;
  const int b = row / 27;
  const int i = row - b * 27;
  const int t = threadIdx.x;

  __shared__ float q_s[64];
  __shared__ float wkr_s[320];
  __shared__ float bk_s[64];
  __shared__ float s_s[28 * 4];
  __shared__ float a_s[28 * 4];
  __shared__ float m_s[32];

  if (t < 64) {
    q_s[t] = QK[(size_t)row * 128 + t];
    bk_s[t] = bk[t];
  }
  for (int idx = t; idx < 320; idx += 128) {
    int a = idx / 5, r = idx - a * 5;
    wkr_s[idx] = Wk[(size_t)a * 261 + 256 + r];
  }
  __syncthreads();

  if (t < 108) {
    const int j = t >> 2, h = t & 3;
    const float* rp = rel + ((size_t)row * 27 + j) * 5;
    const float r0 = rp[0], r1 = rp[1], r2 = rp[2], r3 = rp[3], r4 = rp[4];
    const float* kh = QK + ((size_t)b * 27 + j) * 128 + 64 + h * 16;
    float s = 0.f;
#pragma unroll
    for (int d = 0; d < 16; ++d) {
      const int a = h * 16 + d;
      float kr = wkr_s[a * 5] * r0 + wkr_s[a * 5 + 1] * r1 + wkr_s[a * 5 + 2] * r2 +
                 wkr_s[a * 5 + 3] * r3 + wkr_s[a * 5 + 4] * r4;
      s += q_s[a] * (kh[d] + kr + bk_s[a]);
    }
    s *= 0.25f;
    if (j == i) s = NEGV;
    s_s[j * 4 + h] = s;
  } else if (t < 112) {
    const int h = t - 108;
    float s = 0.f;
#pragma unroll
    for (int d = 0; d < 16; ++d) s += q_s[h * 16 + d] * null_key[h * 16 + d];
    s_s[27 * 4 + h] = s * 0.25f;
  }
  __syncthreads();

  if (t < 4) {
    const int h = t;
    float t0 = -INFINITY, t1 = -INFINITY, t2 = -INFINITY, t3 = -INFINITY;
    for (int j = 0; j < 28; ++j) {
      float v = s_s[j * 4 + h];
      if (v > t0)      { t3 = t2; t2 = t1; t1 = t0; t0 = v; }
      else if (v > t1) { t3 = t2; t2 = t1; t1 = v; }
      else if (v > t2) { t3 = t2; t2 = v; }
      else if (v > t3) { t3 = v; }
    }
    const float thr = t3, mx = t0;
    float sum = 0.f;
    for (int j = 0; j < 28; ++j) {
      float v = s_s[j * 4 + h];
      float e = (v >= thr) ? __expf(v - mx) : 0.f;
      a_s[j * 4 + h] = e;
      sum += e;
    }
    const float inv = 1.f / sum;
    for (int j = 0; j < 28; ++j) a_s[j * 4 + h] *= inv;
  }
  __syncthreads();

  if (t < 32) {
    const int h = t >> 3, v = t & 7;
    float acc = a_s[27 * 4 + h] * null_value[h * 8 + v];
    for (int j = 0; j < 27; ++j)
      acc += a_s[j * 4 + h] * SV[((size_t)b * 27 + j) * 32 + t];
    m_s[t] = acc;
  }
  __syncthreads();

  if (t < 32) {
    float mu = 0.f;
#pragma unroll
    for (int k = 0; k < 32; ++k) mu += m_s[k];
    mu *= (1.f / 32.f);
    float var = 0.f;
#pragma unroll
    for (int k = 0; k < 32; ++k) { float d = m_s[k] - mu; var += d * d; }
    var *= (1.f / 32.f);
    float nv = (m_s[t] - mu) * rsqrtf(var + 1e-5f) * ln_g[t] + ln_b[t];
    FUS[(size_t)row * 288 + 256 + t] = f2bf(nv);
  }
}

// ---------------------------------------------------------------------------
// Final: GD bf16 27648x512 (G1 = cols 0:256, D1 = cols 256:512).
// gate = sigmoid(G1.Wg2+bg2); delta = D1@Wd2^T+bd2; fuse into out.
// ---------------------------------------------------------------------------
__global__ __launch_bounds__(256) void final_kernel(
    const short* __restrict__ GD, const float* __restrict__ Wg2,
    const float* __restrict__ bg2, const float* __restrict__ Wd2,
    const float* __restrict__ bd2, const float* __restrict__ logits,
    float* __restrict__ out) {
  __shared__ float w_s[28 * 257];
  __shared__ float d_row[4][256];
  __shared__ float g_row[4][256];
  const int tid = threadIdx.x;
  for (int idx = tid; idx < 27 * 256; idx += 256) {
    int r = idx >> 8, c = idx & 255;
    w_s[r * 257 + c] = Wd2[idx];
  }
  w_s[27 * 257 + tid] = Wg2[tid];
  __syncthreads();

  const int wave = tid >> 6, lane = tid & 63;
  const int wl = (lane < 28) ? lane : 0;
  const float* wr = w_s + wl * 257;

  for (int rr = 0; rr < 16; ++rr) {
    const int row = blockIdx.x * 64 + rr * 4 + wave;
    // stage row: 512 bf16, 8 per lane; lanes 0-31 -> G half, 32-63 -> D half
    const u32x4 raw = *(const u32x4*)(GD + (size_t)row * 512 + lane * 8);
    float* dst = (lane < 32) ? &g_row[wave][lane * 8] : &d_row[wave][(lane - 32) * 8];
#pragma unroll
    for (int p = 0; p < 4; ++p) {
      unsigned u = raw[p];
      union { float f; unsigned x; } lo, hi;
      lo.x = u << 16;
      hi.x = u & 0xffff0000u;
      dst[2 * p] = lo.f;
      dst[2 * p + 1] = hi.f;
    }
    const float* ar = (lane == 27) ? g_row[wave] : d_row[wave];
    float acc = 0.f;
#pragma unroll 8
    for (int k = 0; k < 256; ++k) acc += ar[k] * wr[k];
    if (lane < 27) acc += bd2[lane];
    else if (lane == 27) acc += bg2[0];
    const float gate = sigmoidf_(__shfl(acc, 27));
    if (lane < 27)
      out[(size_t)row * 33 + 6 + lane] = logits[(size_t)row * 33 + 6 + lane] + 0.1f * gate * acc;
    else if (lane >= 28 && lane < 34)
      out[(size_t)row * 33 + (lane - 28)] = logits[(size_t)row * 33 + (lane - 28)];
  }
}

// ---------------------------------------------------------------------------
extern "C" void kernel_launch(void* const* d_in, const int* in_sizes, int n_in,
                              void* d_out, int out_size, void* d_ws, size_t ws_size,
                              hipStream_t stream) {
  const float* inputs = (const float*)d_in[0];
  const float* hidden = (const float*)d_in[1];
  const float* rel    = (const float*)d_in[2];
  const float* W1  = (const float*)d_in[3];  const float* b1  = (const float*)d_in[4];
  const float* Wih = (const float*)d_in[5];  const float* bih = (const float*)d_in[6];
  const float* Whh = (const float*)d_in[7];  const float* bhh = (const float*)d_in[8];
  const float* Wp1 = (const float*)d_in[9];  const float* bp1 = (const float*)d_in[10];
  const float* Wp2 = (const float*)d_in[11]; const float* bp2 = (const float*)d_in[12];
  const float* Wq  = (const float*)d_in[13]; const float* bq  = (const float*)d_in[14];
  const float* Wk  = (const float*)d_in[15]; const float* bk  = (const float*)d_in[16];
  const float* Wv  = (const float*)d_in[17]; const float* bv  = (const float*)d_in[18];
  const float* ln_g = (const float*)d_in[19]; const float* ln_b = (const float*)d_in[20];
  const float* Wg1 = (const float*)d_in[21]; const float* bg1 = (const float*)d_in[22];
  const float* Wg2 = (const float*)d_in[23]; const float* bg2 = (const float*)d_in[24];
  const float* Wd1 = (const float*)d_in[25]; const float* bd1 = (const float*)d_in[26];
  const float* Wd2 = (const float*)d_in[27]; const float* bd2 = (const float*)d_in[28];
  const float* null_key   = (const float*)d_in[29];
  const float* null_value = (const float*)d_in[30];

  // ---- workspace layout (byte offsets; regions time-multiplexed) ----
  char* wsb = (char*)d_ws;
  // R0 [0, 42467328): GI_b (bf16 27648x768, steps GI..GRU) then GD_b (bf16 27648x512)
  short* GIB = (short*)(wsb + 0);
  short* GDB = (short*)(wsb + 0);
  // R1 [42467328, 84934656): Xin_b (steps conv..W1) / GH_b (GH..GRU) /
  //    then logits(f32)@+0, SV(f32)@+4MiB, QK(f32)@+8MiB
  short* XINB = (short*)(wsb + 42467328);
  short* GHB  = (short*)(wsb + 42467328);
  float* LOG  = (float*)(wsb + 42467328);
  float* SVB  = (float*)(wsb + 42467328 + 4194304);
  float* QKB  = (float*)(wsb + 42467328 + 8388608);
  // R2 [84934656, 115867648): X_b (steps W1..GI) / fusion_b (GRU..GD) @ +0,
  //    hid_b (conv..GH) / P1_b (Wp1..logits) @ +16MiB
  short* XB   = (short*)(wsb + 84934656);
  short* FUS  = (short*)(wsb + 84934656);
  short* HIDB = (short*)(wsb + 84934656 + 16777216);
  short* P1B  = (short*)(wsb + 84934656 + 16777216);
  // Weights (persistent, bf16 + packed fp32 biases)
  char* wb = wsb + 115867648;
  short* W1W  = (short*)(wb + 0);        // 256x352
  short* WIHW = (short*)(wb + 180224);   // 768x256
  short* WHHW = (short*)(wb + 573440);   // 768x256
  short* WP1W = (short*)(wb + 966656);   // 256x256
  short* WP2W = (short*)(wb + 1097728);  // 128x256 (rows>=33 zero)
  short* WQKW = (short*)(wb + 1163264);  // 128x256 ([Wq; Wk_h])
  short* WGDW = (short*)(wb + 1228800);  // 512x288 ([Wg1; Wd1])
  float* BQK  = (float*)(wb + 1523712);  // 128
  float* BGD  = (float*)(wb + 1524224);  // 512

  float* out = (float*)d_out;
  float* H   = out + (size_t)ROWS * 33;  // h output region, fp32

  // 1. convert activations + weights to bf16
  conv_acts<<<65664, 256, 0, stream>>>(inputs, hidden, XINB, HIDB);
  conv_w<<<2979, 256, 0, stream>>>(W1, Wih, Whh, Wp1, Wp2, Wq, Wk, Wg1, Wd1,
                                   bq, bg1, bd1,
                                   W1W, WIHW, WHHW, WP1W, WP2W, WQKW, WGDW, BQK, BGD);
  // 2. X = relu(inputs @ W1^T + b1)            -> bf16
  gemm_mfma<1, 1><<<dim3(2, 216), 256, 0, stream>>>(XINB, 352, W1W, 352, b1, XB, 256, 256, 352);
  // 3. GI = X @ Wih^T + bih                    -> bf16
  gemm_mfma<0, 1><<<dim3(6, 216), 256, 0, stream>>>(XB, 256, WIHW, 256, bih, GIB, 768, 768, 256);
  // 4. GH = hidden @ Whh^T + bhh               -> bf16
  gemm_mfma<0, 1><<<dim3(6, 216), 256, 0, stream>>>(HIDB, 256, WHHW, 256, bhh, GHB, 768, 768, 256);
  // 5. GRU -> H (fp32, d_out) + fusion[:,0:256] (bf16)
  gru_kernel<<<6912, 256, 0, stream>>>(GIB, GHB, hidden, H, FUS);
  // 6. P1 = relu(h @ Wp1^T + bp1)              -> bf16
  gemm_mfma<1, 1><<<dim3(2, 216), 256, 0, stream>>>(FUS, 288, WP1W, 256, bp1, P1B, 256, 256, 256);
  // 7. logits = P1 @ Wp2^T + bp2               -> fp32 (33 cols)
  gemm_mfma<0, 0><<<dim3(1, 216), 256, 0, stream>>>(P1B, 256, WP2W, 256, bp2, LOG, 33, 33, 256);
  // 8. softmax + sender values
  sv_kernel<<<6912, 256, 0, stream>>>(LOG, Wv, bv, SVB);
  // 9. [Q | KH] = h @ [Wq; Wk_h]^T + [bq; 0]   -> fp32 ld 128
  gemm_mfma<0, 0><<<dim3(1, 216), 256, 0, stream>>>(FUS, 288, WQKW, 256, BQK, QKB, 128, 128, 256);
  // 10. attention -> fusion[:,256:288]
  attn_kernel<<<ROWS, 128, 0, stream>>>(QKB, rel, Wk, bk, SVB, null_key, null_value,
                                        ln_g, ln_b, FUS);
  // 11. [G1 | D1] = relu(fusion @ [Wg1; Wd1]^T + [bg1; bd1]) -> bf16 ld 512
  gemm_mfma<1, 1><<<dim3(4, 216), 256, 0, stream>>>(FUS, 288, WGDW, 288, BGD, GDB, 512, 512, 288);
  // 12. final gate/delta/fuse + base copy
  final_kernel<<<432, 256, 0, stream>>>(GDB, Wg2, bg2, Wd2, bd2, LOG, out);
}

// Round 4
// 446.806 us; speedup vs baseline: 4.1712x; 1.1039x over previous
//
#include <hip/hip_runtime.h>
#include <cstdint>
#include <cstddef>

#define ROWS 27648
#define NEGV (-1e10f)

typedef __attribute__((ext_vector_type(8))) short bf16x8;
typedef __attribute__((ext_vector_type(4))) short short4v;
typedef __attribute__((ext_vector_type(4))) float f32x4;

__device__ __forceinline__ float sigmoidf_(float x) { return 1.f / (1.f + __expf(-x)); }
__device__ __forceinline__ float bf2f(short s) {
  union { float f; unsigned u; } x; x.u = ((unsigned)(unsigned short)s) << 16; return x.f;
}
__device__ __forceinline__ short f2bf(float f) {   // RNE
  union { float f; unsigned u; } x; x.f = f;
  unsigned r = (x.u + 0x7fffu + ((x.u >> 16) & 1u)) >> 16;
  return (short)r;
}

// ---------------------------------------------------------------------------
// bf16 MFMA GEMM: C = act(A @ B^T + bias); 128x128 tile, BK=32, 256 thr,
// 4 waves each 64x64 via 4x4 MFMAs. global_load_lds width=16 staging.
// ---------------------------------------------------------------------------
#define GLDS(gp, lp) __builtin_amdgcn_global_load_lds( \
  (const __attribute__((address_space(1))) void*)(gp), \
  (__attribute__((address_space(3))) void*)(lp), 16, 0, 0)

template <int ACT, int BF16OUT>
__global__ __launch_bounds__(256) void gemm_mfma(
    const short* __restrict__ A, int lda,
    const short* __restrict__ B, int ldb,
    const float* __restrict__ bias,
    void* __restrict__ Cv, int ldc, int nstore, int K) {
  __shared__ short As[128 * 32];
  __shared__ short Bs[128 * 32];
  const int tid = threadIdx.x;
  const int wave = tid >> 6, lane = tid & 63;
  const int m0 = blockIdx.y * 128, n0 = blockIdx.x * 128;
  const int srow = lane >> 2, scol = (lane & 3) * 8;
  const int sr0 = wave * 32;
  const int wm = (wave >> 1) * 64, wn = (wave & 1) * 64;
  const int fr = lane & 15, fk = (lane >> 4) * 8;

  f32x4 acc[4][4] = {};

  const short* pA0 = A + (size_t)(m0 + sr0 + srow) * lda + scol;
  const short* pA1 = pA0 + 16 * lda;
  const short* pB0 = B + (size_t)(n0 + sr0 + srow) * ldb + scol;
  const short* pB1 = pB0 + 16 * ldb;
  short* lA0 = &As[sr0 * 32];
  short* lA1 = &As[(sr0 + 16) * 32];
  short* lB0 = &Bs[sr0 * 32];
  short* lB1 = &Bs[(sr0 + 16) * 32];

  for (int k0 = 0; k0 < K; k0 += 32) {
    GLDS(pA0 + k0, lA0);
    GLDS(pA1 + k0, lA1);
    GLDS(pB0 + k0, lB0);
    GLDS(pB1 + k0, lB1);
    __syncthreads();
    bf16x8 af[4], bfr[4];
#pragma unroll
    for (int t = 0; t < 4; ++t) {
      af[t]  = *(const bf16x8*)&As[(wm + t * 16 + fr) * 32 + fk];
      bfr[t] = *(const bf16x8*)&Bs[(wn + t * 16 + fr) * 32 + fk];
    }
#pragma unroll
    for (int i = 0; i < 4; ++i)
#pragma unroll
      for (int j = 0; j < 4; ++j)
        acc[i][j] = __builtin_amdgcn_mfma_f32_16x16x32_bf16(af[i], bfr[j], acc[i][j], 0, 0, 0);
    __syncthreads();
  }

  const int rbase = m0 + wm + (lane >> 4) * 4;
#pragma unroll
  for (int j = 0; j < 4; ++j) {
    const int col = n0 + wn + j * 16 + fr;
    if (col >= nstore) continue;
    const float bv = bias ? bias[col] : 0.f;
#pragma unroll
    for (int i = 0; i < 4; ++i)
#pragma unroll
      for (int r = 0; r < 4; ++r) {
        const int row = rbase + i * 16 + r;
        float v = acc[i][j][r] + bv;
        if (ACT) v = fmaxf(v, 0.f);
        if (BF16OUT) ((short*)Cv)[(size_t)row * ldc + col] = f2bf(v);
        else         ((float*)Cv)[(size_t)row * ldc + col] = v;
      }
  }
}

// ---------------------------------------------------------------------------
// Split-output GEMM for [P1 | QK]: A = FUS (ld 288, K=256), B = WPQK (512x256),
// cols 0:256 -> P1 bf16 relu (ld 256); cols 256:384 -> QK f32 (ld 128).
// ---------------------------------------------------------------------------
__global__ __launch_bounds__(256) void gemm_pqk(
    const short* __restrict__ A, const short* __restrict__ B,
    const float* __restrict__ bias,
    short* __restrict__ P1, float* __restrict__ QK) {
  __shared__ short As[128 * 32];
  __shared__ short Bs[128 * 32];
  const int tid = threadIdx.x;
  const int wave = tid >> 6, lane = tid & 63;
  const int m0 = blockIdx.y * 128, n0 = blockIdx.x * 128;
  const int srow = lane >> 2, scol = (lane & 3) * 8;
  const int sr0 = wave * 32;
  const int wm = (wave >> 1) * 64, wn = (wave & 1) * 64;
  const int fr = lane & 15, fk = (lane >> 4) * 8;

  f32x4 acc[4][4] = {};
  const short* pA0 = A + (size_t)(m0 + sr0 + srow) * 288 + scol;
  const short* pA1 = pA0 + 16 * 288;
  const short* pB0 = B + (size_t)(n0 + sr0 + srow) * 256 + scol;
  const short* pB1 = pB0 + 16 * 256;
  short* lA0 = &As[sr0 * 32];
  short* lA1 = &As[(sr0 + 16) * 32];
  short* lB0 = &Bs[sr0 * 32];
  short* lB1 = &Bs[(sr0 + 16) * 32];

  for (int k0 = 0; k0 < 256; k0 += 32) {
    GLDS(pA0 + k0, lA0);
    GLDS(pA1 + k0, lA1);
    GLDS(pB0 + k0, lB0);
    GLDS(pB1 + k0, lB1);
    __syncthreads();
    bf16x8 af[4], bfr[4];
#pragma unroll
    for (int t = 0; t < 4; ++t) {
      af[t]  = *(const bf16x8*)&As[(wm + t * 16 + fr) * 32 + fk];
      bfr[t] = *(const bf16x8*)&Bs[(wn + t * 16 + fr) * 32 + fk];
    }
#pragma unroll
    for (int i = 0; i < 4; ++i)
#pragma unroll
      for (int j = 0; j < 4; ++j)
        acc[i][j] = __builtin_amdgcn_mfma_f32_16x16x32_bf16(af[i], bfr[j], acc[i][j], 0, 0, 0);
    __syncthreads();
  }

  const int rbase = m0 + wm + (lane >> 4) * 4;
#pragma unroll
  for (int j = 0; j < 4; ++j) {
    const int col = n0 + wn + j * 16 + fr;
    if (col >= 384) continue;
    const float bv = bias[col];
#pragma unroll
    for (int i = 0; i < 4; ++i)
#pragma unroll
      for (int r = 0; r < 4; ++r) {
        const int row = rbase + i * 16 + r;
        float v = acc[i][j][r] + bv;
        if (col < 256) {
          P1[(size_t)row * 256 + col] = f2bf(fmaxf(v, 0.f));
        } else {
          QK[(size_t)row * 128 + (col - 256)] = v;
        }
      }
  }
}

// ---------------------------------------------------------------------------
// Activation conversion: inputs (27648x322 f32) -> padded bf16 27648x352;
// hidden -> bf16.
// ---------------------------------------------------------------------------
__global__ __launch_bounds__(256) void conv_acts(
    const float* __restrict__ inputs, const float* __restrict__ hidden,
    short* __restrict__ xin, short* __restrict__ hid) {
  const int NX = ROWS * 352;
  int idx = blockIdx.x * 256 + threadIdx.x;
  if (idx < NX) {
    int row = idx / 352, c = idx - row * 352;
    xin[idx] = (c < 322) ? f2bf(inputs[row * 322 + c]) : (short)0;
  } else {
    int j = idx - NX;
    if (j < ROWS * 256) hid[j] = f2bf(hidden[j]);
  }
}

// ---------------------------------------------------------------------------
// Weight conversion / packing. Segment sizes (elems):
//  W1W 90112 | WIHW 196608 | WHHW 196608 | WP2W 32768 | WPQK 131072 |
//  WGDW 147456 | WFW 65536 | BPQKb 384 | BGD 512 | BF2 128  = 861184
// ---------------------------------------------------------------------------
__global__ __launch_bounds__(256) void conv_w(
    const float* __restrict__ W1, const float* __restrict__ Wih,
    const float* __restrict__ Whh, const float* __restrict__ Wp1,
    const float* __restrict__ Wp2, const float* __restrict__ Wq,
    const float* __restrict__ Wk, const float* __restrict__ Wg1,
    const float* __restrict__ Wd1, const float* __restrict__ Wg2,
    const float* __restrict__ Wd2, const float* __restrict__ bp1,
    const float* __restrict__ bq, const float* __restrict__ bg1,
    const float* __restrict__ bd1, const float* __restrict__ bg2,
    const float* __restrict__ bd2,
    short* __restrict__ w1w, short* __restrict__ wihw, short* __restrict__ whhw,
    short* __restrict__ wp2w, short* __restrict__ wpqk, short* __restrict__ wgdw,
    short* __restrict__ wfw, float* __restrict__ bpqkb, float* __restrict__ bgd,
    float* __restrict__ bf2v) {
  int idx = blockIdx.x * 256 + threadIdx.x;
  if (idx < 90112) {            // W1: 256x352 padded from 256x322
    int r = idx / 352, c = idx - r * 352;
    w1w[idx] = (c < 322) ? f2bf(W1[r * 322 + c]) : (short)0;
    return;
  }
  idx -= 90112;
  if (idx < 196608) { wihw[idx] = f2bf(Wih[idx]); return; }
  idx -= 196608;
  if (idx < 196608) { whhw[idx] = f2bf(Whh[idx]); return; }
  idx -= 196608;
  if (idx < 32768) {            // Wp2: 128x256, rows >=33 zero
    wp2w[idx] = (idx < 33 * 256) ? f2bf(Wp2[idx]) : (short)0;
    return;
  }
  idx -= 32768;
  if (idx < 131072) {           // WPQK 512x256: [Wp1; Wq; Wk_h; 0]
    int r = idx >> 8, c = idx & 255;
    short v = 0;
    if (r < 256) v = f2bf(Wp1[r * 256 + c]);
    else if (r < 320) v = f2bf(Wq[(r - 256) * 256 + c]);
    else if (r < 384) v = f2bf(Wk[(size_t)(r - 320) * 261 + c]);
    wpqk[idx] = v;
    return;
  }
  idx -= 131072;
  if (idx < 147456) {           // [Wg1 ; Wd1] : 512x288
    wgdw[idx] = (idx < 73728) ? f2bf(Wg1[idx]) : f2bf(Wd1[idx - 73728]);
    return;
  }
  idx -= 147456;
  if (idx < 65536) {            // WFW 128x512: r0 = [Wg2|0]; r1..27 = [0|Wd2]
    int r = idx >> 9, c = idx & 511;
    short v = 0;
    if (r == 0 && c < 256) v = f2bf(Wg2[c]);
    else if (r >= 1 && r < 28 && c >= 256) v = f2bf(Wd2[(r - 1) * 256 + (c - 256)]);
    wfw[idx] = v;
    return;
  }
  idx -= 65536;
  if (idx < 384) {
    bpqkb[idx] = (idx < 256) ? bp1[idx] : ((idx < 320) ? bq[idx - 256] : 0.f);
    return;
  }
  idx -= 384;
  if (idx < 512) { bgd[idx] = (idx < 256) ? bg1[idx] : bd1[idx - 256]; return; }
  idx -= 512;
  if (idx < 128)
    bf2v[idx] = (idx == 0) ? bg2[0] : ((idx < 28) ? bd2[idx - 1] : 0.f);
}

// ---------------------------------------------------------------------------
// GRU elementwise: GI/GH bf16 (biases folded), hidden f32. Writes H f32
// (d_out h region) and h as bf16 into fusion[:, 0:256] (ld 288).
// ---------------------------------------------------------------------------
__global__ __launch_bounds__(256) void gru_kernel(
    const short* __restrict__ GI, const short* __restrict__ GH,
    const float* __restrict__ Hin, float* __restrict__ H,
    short* __restrict__ FUS) {
  int idx = blockIdx.x * 256 + threadIdx.x;
  int row = idx >> 6;
  int c = (idx & 63) * 4;
  const short4v gr = *(const short4v*)(GI + (size_t)row * 768 + c);
  const short4v gz = *(const short4v*)(GI + (size_t)row * 768 + 256 + c);
  const short4v gn = *(const short4v*)(GI + (size_t)row * 768 + 512 + c);
  const short4v hr = *(const short4v*)(GH + (size_t)row * 768 + c);
  const short4v hz = *(const short4v*)(GH + (size_t)row * 768 + 256 + c);
  const short4v hn = *(const short4v*)(GH + (size_t)row * 768 + 512 + c);
  const f32x4 hi = *(const f32x4*)(Hin + (size_t)row * 256 + c);
  f32x4 o;
  short4v ob;
#pragma unroll
  for (int p = 0; p < 4; ++p) {
    float r = sigmoidf_(bf2f(gr[p]) + bf2f(hr[p]));
    float z = sigmoidf_(bf2f(gz[p]) + bf2f(hz[p]));
    float n = tanhf(bf2f(gn[p]) + r * bf2f(hn[p]));
    float h = (1.f - z) * n + z * hi[p];
    o[p] = h;
    ob[p] = f2bf(h);
  }
  *(f32x4*)(H + (size_t)row * 256 + c) = o;
  *(short4v*)(FUS + (size_t)row * 288 + c) = ob;
}

// ---------------------------------------------------------------------------
// Fused sender-values + attention + layernorm. One block (256 thr) per batch
// element b. All per-batch data staged in LDS once.
// ---------------------------------------------------------------------------
__global__ __launch_bounds__(256) void attn_sv_kernel(
    const float* __restrict__ QK, const float* __restrict__ rel,
    const float* __restrict__ Wk, const float* __restrict__ bk,
    const float* __restrict__ LOG, const float* __restrict__ Wv,
    const float* __restrict__ bv, const float* __restrict__ null_key,
    const float* __restrict__ null_value, const float* __restrict__ ln_g,
    const float* __restrict__ ln_b, short* __restrict__ FUS) {
  const int b = blockIdx.x;
  const int t = threadIdx.x;
  __shared__ float qk_s[27 * 129];   // row i: [0:64]=q, [64:128]=key_h (pad->2-way max)
  __shared__ float rel_s[3645];      // rel[b] contiguous 27*27*5
  __shared__ float lg_s[729];        // attack logits [i][j]
  __shared__ float vs_s[27 * 29];    // value_source per sender row
  __shared__ float sv_s[27 * 32];    // sender values
  __shared__ float wv_s[32 * 29];
  __shared__ float wkr_s[320];
  __shared__ float bk_s[64], nk_s[64];
  __shared__ float nv_s[32], bv_s[32], lng_s[32], lnb_s[32];
  __shared__ float s_s[27 * 113];    // scores/alpha [i][j(28)][h] stride 113
  __shared__ float m_s[27 * 32];
  __shared__ float mu_s[27], rs_s[27];

  // ---- stage ----
  for (int idx = t; idx < 27 * 128; idx += 256) {
    int r = idx >> 7, c = idx & 127;
    qk_s[r * 129 + c] = QK[(size_t)(b * 27 + r) * 128 + c];
  }
  for (int idx = t; idx < 3645; idx += 256) rel_s[idx] = rel[(size_t)b * 3645 + idx];
  for (int idx = t; idx < 729; idx += 256) {
    int i = idx / 27, j = idx - i * 27;
    lg_s[idx] = LOG[(size_t)(b * 27 + i) * 33 + 6 + j];
  }
  for (int idx = t; idx < 32 * 29; idx += 256) wv_s[idx] = Wv[idx];
  if (t < 320) { int a = t / 5, r = t - a * 5; wkr_s[t] = Wk[(size_t)a * 261 + 256 + r]; }
  if (t < 64) { bk_s[t] = bk[t]; nk_s[t] = null_key[t]; }
  if (t < 32) { nv_s[t] = null_value[t]; bv_s[t] = bv[t]; lng_s[t] = ln_g[t]; lnb_s[t] = ln_b[t]; }
  __syncthreads();

  // ---- per-sender softmax -> value_source ----
  if (t < 27) {
    float m = -INFINITY;
    for (int j = 0; j < 27; ++j) m = fmaxf(m, lg_s[t * 27 + j]);
    float s = 0.f;
    for (int j = 0; j < 27; ++j) { float e = __expf(lg_s[t * 27 + j] - m); vs_s[t * 29 + j] = e; s += e; }
    float inv = 1.f / s;
    for (int j = 0; j < 27; ++j) vs_s[t * 29 + j] *= inv;
    vs_s[t * 29 + 27] = 1.f;      // can_attack
    vs_s[t * 29 + 28] = inv;      // top1 = max prob
  }
  __syncthreads();

  // ---- sender values ----
  for (int idx = t; idx < 864; idx += 256) {
    int j = idx >> 5, o = idx & 31;
    float acc = bv_s[o];
    const float* w = &wv_s[o * 29];
    const float* v = &vs_s[j * 29];
#pragma unroll
    for (int c = 0; c < 29; ++c) acc += w[c] * v[c];
    sv_s[idx] = acc;
  }
  // ---- scores (independent of sv; same barrier covers both) ----
  for (int idx = t; idx < 3024; idx += 256) {
    int i = idx / 112, r2 = idx - i * 112;
    int j = r2 >> 2, h = r2 & 3;
    float s;
    if (j < 27) {
      const float* rp = &rel_s[(i * 27 + j) * 5];
      float r0 = rp[0], r1 = rp[1], rc = rp[2], r3 = rp[3], r4 = rp[4];
      const float* q = &qk_s[i * 129];
      const float* kh = &qk_s[j * 129 + 64 + h * 16];
      s = 0.f;
#pragma unroll
      for (int d = 0; d < 16; ++d) {
        int a = h * 16 + d;
        float kr = wkr_s[a * 5] * r0 + wkr_s[a * 5 + 1] * r1 + wkr_s[a * 5 + 2] * rc +
                   wkr_s[a * 5 + 3] * r3 + wkr_s[a * 5 + 4] * r4;
        s += q[a] * (kh[d] + kr + bk_s[a]);
      }
      s *= 0.25f;
      if (j == i) s = NEGV;
    } else {
      const float* q = &qk_s[i * 129 + h * 16];
      s = 0.f;
#pragma unroll
      for (int d = 0; d < 16; ++d) s += q[d] * nk_s[h * 16 + d];
      s *= 0.25f;
    }
    s_s[i * 113 + r2] = s;
  }
  __syncthreads();

  // ---- top4 + masked softmax over j(28) per (i,h) ----
  for (int idx = t; idx < 108; idx += 256) {
    int i = idx >> 2, h = idx & 3;
    float* sp = &s_s[i * 113 + h];
    float t0 = -INFINITY, t1 = -INFINITY, t2 = -INFINITY, t3 = -INFINITY;
    for (int j = 0; j < 28; ++j) {
      float v = sp[j * 4];
      if (v > t0)      { t3 = t2; t2 = t1; t1 = t0; t0 = v; }
      else if (v > t1) { t3 = t2; t2 = t1; t1 = v; }
      else if (v > t2) { t3 = t2; t2 = v; }
      else if (v > t3) { t3 = v; }
    }
    float sum = 0.f;
    for (int j = 0; j < 28; ++j) {
      float v = sp[j * 4];
      float e = (v >= t3) ? __expf(v - t0) : 0.f;
      sp[j * 4] = e; sum += e;
    }
    float inv = 1.f / sum;
    for (int j = 0; j < 28; ++j) sp[j * 4] *= inv;
  }
  __syncthreads();

  // ---- messages ----
  for (int idx = t; idx < 864; idx += 256) {
    int i = idx >> 5, o = idx & 31, h = o >> 3;
    const float* al = &s_s[i * 113 + h];
    float acc = al[27 * 4] * nv_s[o];
    for (int j = 0; j < 27; ++j) acc += al[j * 4] * sv_s[j * 32 + o];
    m_s[idx] = acc;
  }
  __syncthreads();

  // ---- layernorm ----
  if (t < 27) {
    float mu = 0.f;
    for (int k = 0; k < 32; ++k) mu += m_s[t * 32 + k];
    mu *= (1.f / 32.f);
    float var = 0.f;
    for (int k = 0; k < 32; ++k) { float d = m_s[t * 32 + k] - mu; var += d * d; }
    var *= (1.f / 32.f);
    mu_s[t] = mu; rs_s[t] = rsqrtf(var + 1e-5f);
  }
  __syncthreads();
  for (int idx = t; idx < 864; idx += 256) {
    int i = idx >> 5, o = idx & 31;
    float nv = (m_s[idx] - mu_s[i]) * rs_s[i] * lng_s[o] + lnb_s[o];
    FUS[(size_t)(b * 27 + i) * 288 + 256 + o] = f2bf(nv);
  }
}

// ---------------------------------------------------------------------------
// Final fuse: gate = sigmoid(GDf[row,0]); out[:, :6] = base;
// out[:, 6+j] = attack + 0.1*gate*GDf[row,1+j].
// ---------------------------------------------------------------------------
__global__ __launch_bounds__(256) void fuse_kernel(
    const float* __restrict__ GDf, const float* __restrict__ LOG,
    float* __restrict__ out) {
  int idx = blockIdx.x * 256 + threadIdx.x;   // over ROWS*33
  int row = idx / 33, c = idx - row * 33;
  float v = LOG[idx];
  if (c >= 6) {
    float gate = sigmoidf_(GDf[(size_t)row * 28]);
    v += 0.1f * gate * GDf[(size_t)row * 28 + (c - 5)];
  }
  out[idx] = v;
}

// ---------------------------------------------------------------------------
extern "C" void kernel_launch(void* const* d_in, const int* in_sizes, int n_in,
                              void* d_out, int out_size, void* d_ws, size_t ws_size,
                              hipStream_t stream) {
  const float* inputs = (const float*)d_in[0];
  const float* hidden = (const float*)d_in[1];
  const float* rel    = (const float*)d_in[2];
  const float* W1  = (const float*)d_in[3];  const float* b1  = (const float*)d_in[4];
  const float* Wih = (const float*)d_in[5];  const float* bih = (const float*)d_in[6];
  const float* Whh = (const float*)d_in[7];  const float* bhh = (const float*)d_in[8];
  const float* Wp1 = (const float*)d_in[9];  const float* bp1 = (const float*)d_in[10];
  const float* Wp2 = (const float*)d_in[11]; const float* bp2 = (const float*)d_in[12];
  const float* Wq  = (const float*)d_in[13]; const float* bq  = (const float*)d_in[14];
  const float* Wk  = (const float*)d_in[15]; const float* bk  = (const float*)d_in[16];
  const float* Wv  = (const float*)d_in[17]; const float* bv  = (const float*)d_in[18];
  const float* ln_g = (const float*)d_in[19]; const float* ln_b = (const float*)d_in[20];
  const float* Wg1 = (const float*)d_in[21]; const float* bg1 = (const float*)d_in[22];
  const float* Wg2 = (const float*)d_in[23]; const float* bg2 = (const float*)d_in[24];
  const float* Wd1 = (const float*)d_in[25]; const float* bd1 = (const float*)d_in[26];
  const float* Wd2 = (const float*)d_in[27]; const float* bd2 = (const float*)d_in[28];
  const float* null_key   = (const float*)d_in[29];
  const float* null_value = (const float*)d_in[30];

  // ---- workspace layout (time-multiplexed regions) ----
  char* wsb = (char*)d_ws;
  // R0 [0, 42467328): GI_b (bf16 27648x768) then GD_b (bf16 27648x512)
  short* GIB = (short*)(wsb + 0);
  short* GDB = (short*)(wsb + 0);
  // R1 [42467328, 84934656): XINB / GHB ; later LOG@+0, QKB@+4MiB, LOGD@+20MiB
  short* XINB = (short*)(wsb + 42467328);
  short* GHB  = (short*)(wsb + 42467328);
  float* LOG  = (float*)(wsb + 42467328);
  float* QKB  = (float*)(wsb + 42467328 + 4194304);
  float* LOGD = (float*)(wsb + 42467328 + 20971520);
  // R2 [84934656, ...): XB / FUS @ +0 ; HIDB / P1B @ +16MiB
  short* XB   = (short*)(wsb + 84934656);
  short* FUS  = (short*)(wsb + 84934656);
  short* HIDB = (short*)(wsb + 84934656 + 16777216);
  short* P1B  = (short*)(wsb + 84934656 + 16777216);
  // Weights (persistent)
  char* wb = wsb + 115867648;
  short* W1W   = (short*)(wb + 0);        // 256x352
  short* WIHW  = (short*)(wb + 180224);   // 768x256
  short* WHHW  = (short*)(wb + 573440);   // 768x256
  short* WP2W  = (short*)(wb + 966656);   // 128x256
  short* WPQK  = (short*)(wb + 1032192);  // 512x256
  short* WGDW  = (short*)(wb + 1294336);  // 512x288
  short* WFW   = (short*)(wb + 1589248);  // 128x512
  float* BPQKb = (float*)(wb + 1720320);  // 384
  float* BGD   = (float*)(wb + 1721856);  // 512
  float* BF2   = (float*)(wb + 1723904);  // 128

  float* out = (float*)d_out;
  float* H   = out + (size_t)ROWS * 33;   // h output region, fp32

  // 1. bf16 conversions / packing
  conv_acts<<<65664, 256, 0, stream>>>(inputs, hidden, XINB, HIDB);
  conv_w<<<3364, 256, 0, stream>>>(W1, Wih, Whh, Wp1, Wp2, Wq, Wk, Wg1, Wd1,
                                   Wg2, Wd2, bp1, bq, bg1, bd1, bg2, bd2,
                                   W1W, WIHW, WHHW, WP2W, WPQK, WGDW, WFW,
                                   BPQKb, BGD, BF2);
  // 2. X = relu(inputs @ W1^T + b1)
  gemm_mfma<1, 1><<<dim3(2, 216), 256, 0, stream>>>(XINB, 352, W1W, 352, b1, XB, 256, 256, 352);
  // 3. GI = X @ Wih^T + bih
  gemm_mfma<0, 1><<<dim3(6, 216), 256, 0, stream>>>(XB, 256, WIHW, 256, bih, GIB, 768, 768, 256);
  // 4. GH = hidden @ Whh^T + bhh
  gemm_mfma<0, 1><<<dim3(6, 216), 256, 0, stream>>>(HIDB, 256, WHHW, 256, bhh, GHB, 768, 768, 256);
  // 5. GRU -> H (fp32, d_out) + fusion[:,0:256] (bf16)
  gru_kernel<<<6912, 256, 0, stream>>>(GIB, GHB, hidden, H, FUS);
  // 6. [P1 | QK] = h @ [Wp1; Wq; Wk_h]^T + [bp1; bq; 0]
  gemm_pqk<<<dim3(3, 216), 256, 0, stream>>>(FUS, WPQK, BPQKb, P1B, QKB);
  // 7. logits = P1 @ Wp2^T + bp2
  gemm_mfma<0, 0><<<dim3(1, 216), 256, 0, stream>>>(P1B, 256, WP2W, 256, bp2, LOG, 33, 33, 256);
  // 8. fused sender-values + attention + LN -> fusion[:,256:288]
  attn_sv_kernel<<<1024, 256, 0, stream>>>(QKB, rel, Wk, bk, LOG, Wv, bv,
                                           null_key, null_value, ln_g, ln_b, FUS);
  // 9. [G1 | D1] = relu(fusion @ [Wg1; Wd1]^T + [bg1; bd1])
  gemm_mfma<1, 1><<<dim3(4, 216), 256, 0, stream>>>(FUS, 288, WGDW, 288, BGD, GDB, 512, 512, 288);
  // 10. GDf = GD @ WFW^T + [bg2; bd2]   (gate logit col 0, delta cols 1:28)
  gemm_mfma<0, 0><<<dim3(1, 216), 256, 0, stream>>>(GDB, 512, WFW, 512, BF2, LOGD, 28, 28, 512);
  // 11. final fuse
  fuse_kernel<<<3564, 256, 0, stream>>>(LOGD, LOG, out);
}

// Round 5
// 445.038 us; speedup vs baseline: 4.1878x; 1.0040x over previous
//
#include <hip/hip_runtime.h>
#include <cstdint>
#include <cstddef>

#define ROWS 27648
#define NEGV (-1e10f)

typedef __attribute__((ext_vector_type(8))) short bf16x8;
typedef __attribute__((ext_vector_type(4))) short short4v;
typedef __attribute__((ext_vector_type(4))) float f32x4;

__device__ __forceinline__ float sigmoidf_(float x) { return 1.f / (1.f + __expf(-x)); }
__device__ __forceinline__ float bf2f(short s) {
  union { float f; unsigned u; } x; x.u = ((unsigned)(unsigned short)s) << 16; return x.f;
}
__device__ __forceinline__ short f2bf(float f) {   // RNE
  union { float f; unsigned u; } x; x.f = f;
  unsigned r = (x.u + 0x7fffu + ((x.u >> 16) & 1u)) >> 16;
  return (short)r;
}

// ---------------------------------------------------------------------------
// bf16 MFMA GEMM: C = act(A @ B^T + bias); 128x128 tile, BK=32, 256 thr,
// 4 waves each 64x64 via 4x4 MFMAs. global_load_lds width=16 staging.
// ---------------------------------------------------------------------------
#define GLDS(gp, lp) __builtin_amdgcn_global_load_lds( \
  (const __attribute__((address_space(1))) void*)(gp), \
  (__attribute__((address_space(3))) void*)(lp), 16, 0, 0)

template <int ACT, int BF16OUT>
__global__ __launch_bounds__(256) void gemm_mfma(
    const short* __restrict__ A, int lda,
    const short* __restrict__ B, int ldb,
    const float* __restrict__ bias,
    void* __restrict__ Cv, int ldc, int nstore, int K) {
  __shared__ short As[128 * 32];
  __shared__ short Bs[128 * 32];
  const int tid = threadIdx.x;
  const int wave = tid >> 6, lane = tid & 63;
  const int m0 = blockIdx.y * 128, n0 = blockIdx.x * 128;
  const int srow = lane >> 2, scol = (lane & 3) * 8;
  const int sr0 = wave * 32;
  const int wm = (wave >> 1) * 64, wn = (wave & 1) * 64;
  const int fr = lane & 15, fk = (lane >> 4) * 8;

  f32x4 acc[4][4] = {};

  const short* pA0 = A + (size_t)(m0 + sr0 + srow) * lda + scol;
  const short* pA1 = pA0 + 16 * lda;
  const short* pB0 = B + (size_t)(n0 + sr0 + srow) * ldb + scol;
  const short* pB1 = pB0 + 16 * ldb;
  short* lA0 = &As[sr0 * 32];
  short* lA1 = &As[(sr0 + 16) * 32];
  short* lB0 = &Bs[sr0 * 32];
  short* lB1 = &Bs[(sr0 + 16) * 32];

  for (int k0 = 0; k0 < K; k0 += 32) {
    GLDS(pA0 + k0, lA0);
    GLDS(pA1 + k0, lA1);
    GLDS(pB0 + k0, lB0);
    GLDS(pB1 + k0, lB1);
    __syncthreads();
    bf16x8 af[4], bfr[4];
#pragma unroll
    for (int t = 0; t < 4; ++t) {
      af[t]  = *(const bf16x8*)&As[(wm + t * 16 + fr) * 32 + fk];
      bfr[t] = *(const bf16x8*)&Bs[(wn + t * 16 + fr) * 32 + fk];
    }
#pragma unroll
    for (int i = 0; i < 4; ++i)
#pragma unroll
      for (int j = 0; j < 4; ++j)
        acc[i][j] = __builtin_amdgcn_mfma_f32_16x16x32_bf16(af[i], bfr[j], acc[i][j], 0, 0, 0);
    __syncthreads();
  }

  const int rbase = m0 + wm + (lane >> 4) * 4;
#pragma unroll
  for (int j = 0; j < 4; ++j) {
    const int col = n0 + wn + j * 16 + fr;
    if (col >= nstore) continue;
    const float bv = bias ? bias[col] : 0.f;
#pragma unroll
    for (int i = 0; i < 4; ++i)
#pragma unroll
      for (int r = 0; r < 4; ++r) {
        const int row = rbase + i * 16 + r;
        float v = acc[i][j][r] + bv;
        if (ACT) v = fmaxf(v, 0.f);
        if (BF16OUT) ((short*)Cv)[(size_t)row * ldc + col] = f2bf(v);
        else         ((float*)Cv)[(size_t)row * ldc + col] = v;
      }
  }
}

// ---------------------------------------------------------------------------
// Split-output GEMM for [P1 | QK]: A = FUS (ld 288, K=256), B = WPQK (512x256),
// cols 0:256 -> P1 bf16 relu (ld 256); cols 256:384 -> QK f32 (ld 128).
// ---------------------------------------------------------------------------
__global__ __launch_bounds__(256) void gemm_pqk(
    const short* __restrict__ A, const short* __restrict__ B,
    const float* __restrict__ bias,
    short* __restrict__ P1, float* __restrict__ QK) {
  __shared__ short As[128 * 32];
  __shared__ short Bs[128 * 32];
  const int tid = threadIdx.x;
  const int wave = tid >> 6, lane = tid & 63;
  const int m0 = blockIdx.y * 128, n0 = blockIdx.x * 128;
  const int srow = lane >> 2, scol = (lane & 3) * 8;
  const int sr0 = wave * 32;
  const int wm = (wave >> 1) * 64, wn = (wave & 1) * 64;
  const int fr = lane & 15, fk = (lane >> 4) * 8;

  f32x4 acc[4][4] = {};
  const short* pA0 = A + (size_t)(m0 + sr0 + srow) * 288 + scol;
  const short* pA1 = pA0 + 16 * 288;
  const short* pB0 = B + (size_t)(n0 + sr0 + srow) * 256 + scol;
  const short* pB1 = pB0 + 16 * 256;
  short* lA0 = &As[sr0 * 32];
  short* lA1 = &As[(sr0 + 16) * 32];
  short* lB0 = &Bs[sr0 * 32];
  short* lB1 = &Bs[(sr0 + 16) * 32];

  for (int k0 = 0; k0 < 256; k0 += 32) {
    GLDS(pA0 + k0, lA0);
    GLDS(pA1 + k0, lA1);
    GLDS(pB0 + k0, lB0);
    GLDS(pB1 + k0, lB1);
    __syncthreads();
    bf16x8 af[4], bfr[4];
#pragma unroll
    for (int t = 0; t < 4; ++t) {
      af[t]  = *(const bf16x8*)&As[(wm + t * 16 + fr) * 32 + fk];
      bfr[t] = *(const bf16x8*)&Bs[(wn + t * 16 + fr) * 32 + fk];
    }
#pragma unroll
    for (int i = 0; i < 4; ++i)
#pragma unroll
      for (int j = 0; j < 4; ++j)
        acc[i][j] = __builtin_amdgcn_mfma_f32_16x16x32_bf16(af[i], bfr[j], acc[i][j], 0, 0, 0);
    __syncthreads();
  }

  const int rbase = m0 + wm + (lane >> 4) * 4;
#pragma unroll
  for (int j = 0; j < 4; ++j) {
    const int col = n0 + wn + j * 16 + fr;
    if (col >= 384) continue;
    const float bv = bias[col];
#pragma unroll
    for (int i = 0; i < 4; ++i)
#pragma unroll
      for (int r = 0; r < 4; ++r) {
        const int row = rbase + i * 16 + r;
        float v = acc[i][j][r] + bv;
        if (col < 256) {
          P1[(size_t)row * 256 + col] = f2bf(fmaxf(v, 0.f));
        } else {
          QK[(size_t)row * 128 + (col - 256)] = v;
        }
      }
  }
}

// ---------------------------------------------------------------------------
// Activation conversion.
// ---------------------------------------------------------------------------
__global__ __launch_bounds__(256) void conv_acts(
    const float* __restrict__ inputs, const float* __restrict__ hidden,
    short* __restrict__ xin, short* __restrict__ hid) {
  const int NX = ROWS * 352;
  int idx = blockIdx.x * 256 + threadIdx.x;
  if (idx < NX) {
    int row = idx / 352, c = idx - row * 352;
    xin[idx] = (c < 322) ? f2bf(inputs[row * 322 + c]) : (short)0;
  } else {
    int j = idx - NX;
    if (j < ROWS * 256) hid[j] = f2bf(hidden[j]);
  }
}

// ---------------------------------------------------------------------------
// Weight conversion / packing.
// ---------------------------------------------------------------------------
__global__ __launch_bounds__(256) void conv_w(
    const float* __restrict__ W1, const float* __restrict__ Wih,
    const float* __restrict__ Whh, const float* __restrict__ Wp1,
    const float* __restrict__ Wp2, const float* __restrict__ Wq,
    const float* __restrict__ Wk, const float* __restrict__ Wg1,
    const float* __restrict__ Wd1, const float* __restrict__ Wg2,
    const float* __restrict__ Wd2, const float* __restrict__ bp1,
    const float* __restrict__ bq, const float* __restrict__ bg1,
    const float* __restrict__ bd1, const float* __restrict__ bg2,
    const float* __restrict__ bd2,
    short* __restrict__ w1w, short* __restrict__ wihw, short* __restrict__ whhw,
    short* __restrict__ wp2w, short* __restrict__ wpqk, short* __restrict__ wgdw,
    short* __restrict__ wfw, float* __restrict__ bpqkb, float* __restrict__ bgd,
    float* __restrict__ bf2v) {
  int idx = blockIdx.x * 256 + threadIdx.x;
  if (idx < 90112) {
    int r = idx / 352, c = idx - r * 352;
    w1w[idx] = (c < 322) ? f2bf(W1[r * 322 + c]) : (short)0;
    return;
  }
  idx -= 90112;
  if (idx < 196608) { wihw[idx] = f2bf(Wih[idx]); return; }
  idx -= 196608;
  if (idx < 196608) { whhw[idx] = f2bf(Whh[idx]); return; }
  idx -= 196608;
  if (idx < 32768) {
    wp2w[idx] = (idx < 33 * 256) ? f2bf(Wp2[idx]) : (short)0;
    return;
  }
  idx -= 32768;
  if (idx < 131072) {           // WPQK 512x256: [Wp1; Wq; Wk_h; 0]
    int r = idx >> 8, c = idx & 255;
    short v = 0;
    if (r < 256) v = f2bf(Wp1[r * 256 + c]);
    else if (r < 320) v = f2bf(Wq[(r - 256) * 256 + c]);
    else if (r < 384) v = f2bf(Wk[(size_t)(r - 320) * 261 + c]);
    wpqk[idx] = v;
    return;
  }
  idx -= 131072;
  if (idx < 147456) {           // [Wg1 ; Wd1] : 512x288
    wgdw[idx] = (idx < 73728) ? f2bf(Wg1[idx]) : f2bf(Wd1[idx - 73728]);
    return;
  }
  idx -= 147456;
  if (idx < 65536) {            // WFW 128x512: r0 = [Wg2|0]; r1..27 = [0|Wd2]
    int r = idx >> 9, c = idx & 511;
    short v = 0;
    if (r == 0 && c < 256) v = f2bf(Wg2[c]);
    else if (r >= 1 && r < 28 && c >= 256) v = f2bf(Wd2[(r - 1) * 256 + (c - 256)]);
    wfw[idx] = v;
    return;
  }
  idx -= 65536;
  if (idx < 384) {
    bpqkb[idx] = (idx < 256) ? bp1[idx] : ((idx < 320) ? bq[idx - 256] : 0.f);
    return;
  }
  idx -= 384;
  if (idx < 512) { bgd[idx] = (idx < 256) ? bg1[idx] : bd1[idx - 256]; return; }
  idx -= 512;
  if (idx < 128)
    bf2v[idx] = (idx == 0) ? bg2[0] : ((idx < 28) ? bd2[idx - 1] : 0.f);
}

// ---------------------------------------------------------------------------
// GRU elementwise.
// ---------------------------------------------------------------------------
__global__ __launch_bounds__(256) void gru_kernel(
    const short* __restrict__ GI, const short* __restrict__ GH,
    const float* __restrict__ Hin, float* __restrict__ H,
    short* __restrict__ FUS) {
  int idx = blockIdx.x * 256 + threadIdx.x;
  int row = idx >> 6;
  int c = (idx & 63) * 4;
  const short4v gr = *(const short4v*)(GI + (size_t)row * 768 + c);
  const short4v gz = *(const short4v*)(GI + (size_t)row * 768 + 256 + c);
  const short4v gn = *(const short4v*)(GI + (size_t)row * 768 + 512 + c);
  const short4v hr = *(const short4v*)(GH + (size_t)row * 768 + c);
  const short4v hz = *(const short4v*)(GH + (size_t)row * 768 + 256 + c);
  const short4v hn = *(const short4v*)(GH + (size_t)row * 768 + 512 + c);
  const f32x4 hi = *(const f32x4*)(Hin + (size_t)row * 256 + c);
  f32x4 o;
  short4v ob;
#pragma unroll
  for (int p = 0; p < 4; ++p) {
    float r = sigmoidf_(bf2f(gr[p]) + bf2f(hr[p]));
    float z = sigmoidf_(bf2f(gz[p]) + bf2f(hz[p]));
    float n = tanhf(bf2f(gn[p]) + r * bf2f(hn[p]));
    float h = (1.f - z) * n + z * hi[p];
    o[p] = h;
    ob[p] = f2bf(h);
  }
  *(f32x4*)(H + (size_t)row * 256 + c) = o;
  *(short4v*)(FUS + (size_t)row * 288 + c) = ob;
}

// ---------------------------------------------------------------------------
// Per-row softmax over attack logits -> value_source -> sender_values (32).
// One wave per row, 4 rows per block.
// ---------------------------------------------------------------------------
__global__ __launch_bounds__(256) void sv_kernel(
    const float* __restrict__ logits, const float* __restrict__ Wv,
    const float* __restrict__ bv, float* __restrict__ SV) {
  const int wave = threadIdx.x >> 6;
  const int lane = threadIdx.x & 63;
  const int row = blockIdx.x * 4 + wave;
  __shared__ float vs_s[4][29];
  float v = (lane < 27) ? logits[(size_t)row * 33 + 6 + lane] : -INFINITY;
  float m = v;
#pragma unroll
  for (int off = 32; off; off >>= 1) m = fmaxf(m, __shfl_xor(m, off));
  float e = (lane < 27) ? __expf(v - m) : 0.f;
  float s = e;
#pragma unroll
  for (int off = 32; off; off >>= 1) s += __shfl_xor(s, off);
  if (lane < 27) vs_s[wave][lane] = e / s;
  if (lane == 27) vs_s[wave][27] = 1.f;
  if (lane == 28) vs_s[wave][28] = 1.f / s;   // top1 = max prob
  __syncthreads();
  if (lane < 32) {
    float acc = bv[lane];
    const float* w = Wv + lane * 29;
#pragma unroll
    for (int c = 0; c < 29; ++c) acc += w[c] * vs_s[wave][c];
    SV[(size_t)row * 32 + lane] = acc;
  }
}

// ---------------------------------------------------------------------------
// Attention v2: one WAVE per (b,i) row; block = (b, quad of i), 7168 blocks.
// qWkr factorization: score(i,j,h) = 0.25*( q_i[h]·kh_j[h]
//        + sum_r rel[b,i,j,r]*qwkr[h,r] + qbk[h] ), null = 0.25*qnull[h].
// Block stages kh(27x64), SV(27x32), Wkr/bk/nk/nv/ln once (~17.5 KB LDS).
// ---------------------------------------------------------------------------
__global__ __launch_bounds__(256) void attn2_kernel(
    const float* __restrict__ QK, const float* __restrict__ rel,
    const float* __restrict__ Wk, const float* __restrict__ bk,
    const float* __restrict__ SV, const float* __restrict__ null_key,
    const float* __restrict__ null_value, const float* __restrict__ ln_g,
    const float* __restrict__ ln_b, short* __restrict__ FUS) {
  const int b  = blockIdx.x / 7;
  const int iq = blockIdx.x - b * 7;
  const int t = threadIdx.x;
  const int wave = t >> 6, lane = t & 63;
  const int i = iq * 4 + wave;          // 0..27 (27 invalid)
  const int iw = (i < 27) ? i : 26;     // clamped for safe reads

  __shared__ float kh_s[27 * 64];
  __shared__ float sv_s[27 * 32];
  __shared__ float q_s[4][64];
  __shared__ float wkr_s[320];
  __shared__ float bk_s[64], nk_s[64];
  __shared__ float nv_s[32], lng_s[32], lnb_s[32];
  __shared__ float rel_s[4][136];
  __shared__ float qws[4][28];          // [0:20) qwkr h*5+r | [20:24) qbk | [24:28) qnull
  __shared__ float s_row[4][112];

  // ---- block stage ----
  for (int idx = t; idx < 27 * 64; idx += 256) {
    int r = idx >> 6, c = idx & 63;
    kh_s[idx] = QK[(size_t)(b * 27 + r) * 128 + 64 + c];
  }
  for (int idx = t; idx < 27 * 32; idx += 256)
    sv_s[idx] = SV[(size_t)b * 864 + idx];
  q_s[wave][lane] = QK[(size_t)(b * 27 + iw) * 128 + lane];
  if (t < 320) { int a = t / 5, r = t - a * 5; wkr_s[t] = Wk[(size_t)a * 261 + 256 + r]; }
  if (t >= 320 && t < 384) bk_s[t - 320] = bk[t - 320];
  if (t >= 384 && t < 448) nk_s[t - 384] = null_key[t - 384];
  if (t >= 448 && t < 480) nv_s[t - 448] = null_value[t - 448];
  if (t >= 480 && t < 512) { lng_s[t - 480] = ln_g[t - 480]; lnb_s[t - 480] = ln_b[t - 480]; }
  // per-wave rel row: rel[b, iw, :, :] = 135 floats
  for (int idx = lane; idx < 135; idx += 64)
    rel_s[wave][idx] = rel[(size_t)(b * 27 + iw) * 135 + idx];
  __syncthreads();

  // ---- per-wave precompute: qwkr, qbk, qnull ----
  if (lane < 28) {
    float acc = 0.f;
    if (lane < 20) {
      const int h = lane / 5, r = lane - h * 5;
#pragma unroll
      for (int d = 0; d < 16; ++d)
        acc += q_s[wave][h * 16 + d] * wkr_s[(h * 16 + d) * 5 + r];
    } else if (lane < 24) {
      const int h = lane - 20;
#pragma unroll
      for (int d = 0; d < 16; ++d)
        acc += q_s[wave][h * 16 + d] * bk_s[h * 16 + d];
    } else {
      const int h = lane - 24;
#pragma unroll
      for (int d = 0; d < 16; ++d)
        acc += q_s[wave][h * 16 + d] * nk_s[h * 16 + d];
    }
    qws[wave][lane] = acc;
  }
  __syncthreads();

  // ---- scores: 112 items (28 j x 4 h) per wave, 2 lane-passes ----
#pragma unroll
  for (int pass = 0; pass < 2; ++pass) {
    const int item = pass * 64 + lane;
    if (item < 112) {
      const int j = item >> 2, h = item & 3;
      float s;
      if (j < 27) {
        float acc = qws[wave][20 + h];
        const float* q  = &q_s[wave][h * 16];
        const float* kh = &kh_s[j * 64 + h * 16];
#pragma unroll
        for (int d = 0; d < 16; ++d) acc += q[d] * kh[d];
        const float* rp = &rel_s[wave][j * 5];
        const float* qw = &qws[wave][h * 5];
#pragma unroll
        for (int r = 0; r < 5; ++r) acc += rp[r] * qw[r];
        s = acc * 0.25f;
        if (j == i) s = NEGV;
      } else {
        s = qws[wave][24 + h] * 0.25f;
      }
      s_row[wave][item] = s;
    }
  }
  __syncthreads();

  // ---- top4 + masked softmax over 28 per (i,h): lanes 0..3 ----
  if (lane < 4) {
    float* sp = &s_row[wave][lane];
    float t0 = -INFINITY, t1 = -INFINITY, t2 = -INFINITY, t3 = -INFINITY;
    for (int j = 0; j < 28; ++j) {
      float v = sp[j * 4];
      if (v > t0)      { t3 = t2; t2 = t1; t1 = t0; t0 = v; }
      else if (v > t1) { t3 = t2; t2 = t1; t1 = v; }
      else if (v > t2) { t3 = t2; t2 = v; }
      else if (v > t3) { t3 = v; }
    }
    float sum = 0.f;
    for (int j = 0; j < 28; ++j) {
      float v = sp[j * 4];
      float e = (v >= t3) ? __expf(v - t0) : 0.f;
      sp[j * 4] = e; sum += e;
    }
    const float inv = 1.f / sum;
    for (int j = 0; j < 28; ++j) sp[j * 4] *= inv;
  }
  __syncthreads();

  // ---- messages + layernorm: lanes 0..31 ----
  if (lane < 32) {
    const int h = lane >> 3;
    const float* al = &s_row[wave][h];
    float acc = al[27 * 4] * nv_s[lane];
    for (int j = 0; j < 27; ++j) acc += al[j * 4] * sv_s[j * 32 + lane];
    // mean over 32 lanes
    float sum = acc;
#pragma unroll
    for (int off = 16; off; off >>= 1) sum += __shfl_xor(sum, off);
    const float mu = sum * (1.f / 32.f);
    float d = acc - mu;
    float sq = d * d;
#pragma unroll
    for (int off = 16; off; off >>= 1) sq += __shfl_xor(sq, off);
    const float rs = rsqrtf(sq * (1.f / 32.f) + 1e-5f);
    const float nv = d * rs * lng_s[lane] + lnb_s[lane];
    if (i < 27)
      FUS[(size_t)(b * 27 + i) * 288 + 256 + lane] = f2bf(nv);
  }
}

// ---------------------------------------------------------------------------
// Final fuse: gate = sigmoid(GDf[row,0]); out[:, :6] = base;
// out[:, 6+j] = attack + 0.1*gate*GDf[row,1+j].
// ---------------------------------------------------------------------------
__global__ __launch_bounds__(256) void fuse_kernel(
    const float* __restrict__ GDf, const float* __restrict__ LOG,
    float* __restrict__ out) {
  int idx = blockIdx.x * 256 + threadIdx.x;   // over ROWS*33
  int row = idx / 33, c = idx - row * 33;
  float v = LOG[idx];
  if (c >= 6) {
    float gate = sigmoidf_(GDf[(size_t)row * 28]);
    v += 0.1f * gate * GDf[(size_t)row * 28 + (c - 5)];
  }
  out[idx] = v;
}

// ---------------------------------------------------------------------------
extern "C" void kernel_launch(void* const* d_in, const int* in_sizes, int n_in,
                              void* d_out, int out_size, void* d_ws, size_t ws_size,
                              hipStream_t stream) {
  const float* inputs = (const float*)d_in[0];
  const float* hidden = (const float*)d_in[1];
  const float* rel    = (const float*)d_in[2];
  const float* W1  = (const float*)d_in[3];  const float* b1  = (const float*)d_in[4];
  const float* Wih = (const float*)d_in[5];  const float* bih = (const float*)d_in[6];
  const float* Whh = (const float*)d_in[7];  const float* bhh = (const float*)d_in[8];
  const float* Wp1 = (const float*)d_in[9];  const float* bp1 = (const float*)d_in[10];
  const float* Wp2 = (const float*)d_in[11]; const float* bp2 = (const float*)d_in[12];
  const float* Wq  = (const float*)d_in[13]; const float* bq  = (const float*)d_in[14];
  const float* Wk  = (const float*)d_in[15]; const float* bk  = (const float*)d_in[16];
  const float* Wv  = (const float*)d_in[17]; const float* bv  = (const float*)d_in[18];
  const float* ln_g = (const float*)d_in[19]; const float* ln_b = (const float*)d_in[20];
  const float* Wg1 = (const float*)d_in[21]; const float* bg1 = (const float*)d_in[22];
  const float* Wg2 = (const float*)d_in[23]; const float* bg2 = (const float*)d_in[24];
  const float* Wd1 = (const float*)d_in[25]; const float* bd1 = (const float*)d_in[26];
  const float* Wd2 = (const float*)d_in[27]; const float* bd2 = (const float*)d_in[28];
  const float* null_key   = (const float*)d_in[29];
  const float* null_value = (const float*)d_in[30];

  // ---- workspace layout (time-multiplexed regions) ----
  char* wsb = (char*)d_ws;
  short* GIB = (short*)(wsb + 0);
  short* GDB = (short*)(wsb + 0);
  short* XINB = (short*)(wsb + 42467328);
  short* GHB  = (short*)(wsb + 42467328);
  float* LOG  = (float*)(wsb + 42467328);
  float* QKB  = (float*)(wsb + 42467328 + 4194304);
  float* SVB  = (float*)(wsb + 42467328 + 16777216);
  float* LOGD = (float*)(wsb + 42467328 + 20971520);
  short* XB   = (short*)(wsb + 84934656);
  short* FUS  = (short*)(wsb + 84934656);
  short* HIDB = (short*)(wsb + 84934656 + 16777216);
  short* P1B  = (short*)(wsb + 84934656 + 16777216);
  // Weights (persistent)
  char* wb = wsb + 115867648;
  short* W1W   = (short*)(wb + 0);        // 256x352
  short* WIHW  = (short*)(wb + 180224);   // 768x256
  short* WHHW  = (short*)(wb + 573440);   // 768x256
  short* WP2W  = (short*)(wb + 966656);   // 128x256
  short* WPQK  = (short*)(wb + 1032192);  // 512x256
  short* WGDW  = (short*)(wb + 1294336);  // 512x288
  short* WFW   = (short*)(wb + 1589248);  // 128x512
  float* BPQKb = (float*)(wb + 1720320);  // 384
  float* BGD   = (float*)(wb + 1721856);  // 512
  float* BF2   = (float*)(wb + 1723904);  // 128

  float* out = (float*)d_out;
  float* H   = out + (size_t)ROWS * 33;   // h output region, fp32

  // 1. bf16 conversions / packing
  conv_acts<<<65664, 256, 0, stream>>>(inputs, hidden, XINB, HIDB);
  conv_w<<<3364, 256, 0, stream>>>(W1, Wih, Whh, Wp1, Wp2, Wq, Wk, Wg1, Wd1,
                                   Wg2, Wd2, bp1, bq, bg1, bd1, bg2, bd2,
                                   W1W, WIHW, WHHW, WP2W, WPQK, WGDW, WFW,
                                   BPQKb, BGD, BF2);
  // 2. X = relu(inputs @ W1^T + b1)
  gemm_mfma<1, 1><<<dim3(2, 216), 256, 0, stream>>>(XINB, 352, W1W, 352, b1, XB, 256, 256, 352);
  // 3. GI = X @ Wih^T + bih
  gemm_mfma<0, 1><<<dim3(6, 216), 256, 0, stream>>>(XB, 256, WIHW, 256, bih, GIB, 768, 768, 256);
  // 4. GH = hidden @ Whh^T + bhh
  gemm_mfma<0, 1><<<dim3(6, 216), 256, 0, stream>>>(HIDB, 256, WHHW, 256, bhh, GHB, 768, 768, 256);
  // 5. GRU -> H (fp32, d_out) + fusion[:,0:256] (bf16)
  gru_kernel<<<6912, 256, 0, stream>>>(GIB, GHB, hidden, H, FUS);
  // 6. [P1 | QK] = h @ [Wp1; Wq; Wk_h]^T + [bp1; bq; 0]
  gemm_pqk<<<dim3(3, 216), 256, 0, stream>>>(FUS, WPQK, BPQKb, P1B, QKB);
  // 7. logits = P1 @ Wp2^T + bp2
  gemm_mfma<0, 0><<<dim3(1, 216), 256, 0, stream>>>(P1B, 256, WP2W, 256, bp2, LOG, 33, 33, 256);
  // 8. sender values
  sv_kernel<<<6912, 256, 0, stream>>>(LOG, Wv, bv, SVB);
  // 9. attention v2 -> fusion[:,256:288]
  attn2_kernel<<<7168, 256, 0, stream>>>(QKB, rel, Wk, bk, SVB, null_key,
                                         null_value, ln_g, ln_b, FUS);
  // 10. [G1 | D1] = relu(fusion @ [Wg1; Wd1]^T + [bg1; bd1])
  gemm_mfma<1, 1><<<dim3(4, 216), 256, 0, stream>>>(FUS, 288, WGDW, 288, BGD, GDB, 512, 512, 288);
  // 11. GDf = GD @ WFW^T + [bg2; bd2]
  gemm_mfma<0, 0><<<dim3(1, 216), 256, 0, stream>>>(GDB, 512, WFW, 512, BF2, LOGD, 28, 28, 512);
  // 12. final fuse
  fuse_kernel<<<3564, 256, 0, stream>>>(LOGD, LOG, out);
}

// Round 7
// 430.227 us; speedup vs baseline: 4.3320x; 1.0344x over previous
//
#include <hip/hip_runtime.h>
#include <cstdint>
#include <cstddef>

#define ROWS 27648
#define NEGV (-1e10f)

typedef __attribute__((ext_vector_type(8))) short bf16x8;
typedef __attribute__((ext_vector_type(4))) short short4v;
typedef __attribute__((ext_vector_type(4))) float f32x4;

__device__ __forceinline__ float sigmoidf_(float x) { return 1.f / (1.f + __expf(-x)); }
__device__ __forceinline__ float bf2f(short s) {
  union { float f; unsigned u; } x; x.u = ((unsigned)(unsigned short)s) << 16; return x.f;
}
__device__ __forceinline__ short f2bf(float f) {   // RNE
  union { float f; unsigned u; } x; x.f = f;
  unsigned r = (x.u + 0x7fffu + ((x.u >> 16) & 1u)) >> 16;
  return (short)r;
}

// ---------------------------------------------------------------------------
// bf16 MFMA GEMM: C = act(A @ B^T + bias); 128x128 tile, BK=32, 256 thr.
// Grid: (216 row-tiles, n col-tiles): same-A-slab blocks are id-congruent
// mod 8 => same XCD L2.
// ---------------------------------------------------------------------------
#define GLDS(gp, lp) __builtin_amdgcn_global_load_lds( \
  (const __attribute__((address_space(1))) void*)(gp), \
  (__attribute__((address_space(3))) void*)(lp), 16, 0, 0)

template <int ACT, int BF16OUT>
__global__ __launch_bounds__(256) void gemm_mfma(
    const short* __restrict__ A, int lda,
    const short* __restrict__ B, int ldb,
    const float* __restrict__ bias,
    void* __restrict__ Cv, int ldc, int nstore, int K) {
  __shared__ short As[128 * 32];
  __shared__ short Bs[128 * 32];
  const int tid = threadIdx.x;
  const int wave = tid >> 6, lane = tid & 63;
  const int m0 = blockIdx.x * 128, n0 = blockIdx.y * 128;
  const int srow = lane >> 2, scol = (lane & 3) * 8;
  const int sr0 = wave * 32;
  const int wm = (wave >> 1) * 64, wn = (wave & 1) * 64;
  const int fr = lane & 15, fk = (lane >> 4) * 8;

  f32x4 acc[4][4] = {};

  const short* pA0 = A + (size_t)(m0 + sr0 + srow) * lda + scol;
  const short* pA1 = pA0 + 16 * lda;
  const short* pB0 = B + (size_t)(n0 + sr0 + srow) * ldb + scol;
  const short* pB1 = pB0 + 16 * ldb;
  short* lA0 = &As[sr0 * 32];
  short* lA1 = &As[(sr0 + 16) * 32];
  short* lB0 = &Bs[sr0 * 32];
  short* lB1 = &Bs[(sr0 + 16) * 32];

  for (int k0 = 0; k0 < K; k0 += 32) {
    GLDS(pA0 + k0, lA0);
    GLDS(pA1 + k0, lA1);
    GLDS(pB0 + k0, lB0);
    GLDS(pB1 + k0, lB1);
    __syncthreads();
    bf16x8 af[4], bfr[4];
#pragma unroll
    for (int t = 0; t < 4; ++t) {
      af[t]  = *(const bf16x8*)&As[(wm + t * 16 + fr) * 32 + fk];
      bfr[t] = *(const bf16x8*)&Bs[(wn + t * 16 + fr) * 32 + fk];
    }
#pragma unroll
    for (int i = 0; i < 4; ++i)
#pragma unroll
      for (int j = 0; j < 4; ++j)
        acc[i][j] = __builtin_amdgcn_mfma_f32_16x16x32_bf16(af[i], bfr[j], acc[i][j], 0, 0, 0);
    __syncthreads();
  }

  const int rbase = m0 + wm + (lane >> 4) * 4;
#pragma unroll
  for (int j = 0; j < 4; ++j) {
    const int col = n0 + wn + j * 16 + fr;
    if (col >= nstore) continue;
    const float bv = bias ? bias[col] : 0.f;
#pragma unroll
    for (int i = 0; i < 4; ++i)
#pragma unroll
      for (int r = 0; r < 4; ++r) {
        const int row = rbase + i * 16 + r;
        float v = acc[i][j][r] + bv;
        if (ACT) v = fmaxf(v, 0.f);
        if (BF16OUT) ((short*)Cv)[(size_t)row * ldc + col] = f2bf(v);
        else         ((float*)Cv)[(size_t)row * ldc + col] = v;
      }
  }
}

// ---------------------------------------------------------------------------
// Split-output GEMM for [P1 | QK].
// ---------------------------------------------------------------------------
__global__ __launch_bounds__(256) void gemm_pqk(
    const short* __restrict__ A, const short* __restrict__ B,
    const float* __restrict__ bias,
    short* __restrict__ P1, float* __restrict__ QK) {
  __shared__ short As[128 * 32];
  __shared__ short Bs[128 * 32];
  const int tid = threadIdx.x;
  const int wave = tid >> 6, lane = tid & 63;
  const int m0 = blockIdx.x * 128, n0 = blockIdx.y * 128;
  const int srow = lane >> 2, scol = (lane & 3) * 8;
  const int sr0 = wave * 32;
  const int wm = (wave >> 1) * 64, wn = (wave & 1) * 64;
  const int fr = lane & 15, fk = (lane >> 4) * 8;

  f32x4 acc[4][4] = {};
  const short* pA0 = A + (size_t)(m0 + sr0 + srow) * 288 + scol;
  const short* pA1 = pA0 + 16 * 288;
  const short* pB0 = B + (size_t)(n0 + sr0 + srow) * 256 + scol;
  const short* pB1 = pB0 + 16 * 256;
  short* lA0 = &As[sr0 * 32];
  short* lA1 = &As[(sr0 + 16) * 32];
  short* lB0 = &Bs[sr0 * 32];
  short* lB1 = &Bs[(sr0 + 16) * 32];

  for (int k0 = 0; k0 < 256; k0 += 32) {
    GLDS(pA0 + k0, lA0);
    GLDS(pA1 + k0, lA1);
    GLDS(pB0 + k0, lB0);
    GLDS(pB1 + k0, lB1);
    __syncthreads();
    bf16x8 af[4], bfr[4];
#pragma unroll
    for (int t = 0; t < 4; ++t) {
      af[t]  = *(const bf16x8*)&As[(wm + t * 16 + fr) * 32 + fk];
      bfr[t] = *(const bf16x8*)&Bs[(wn + t * 16 + fr) * 32 + fk];
    }
#pragma unroll
    for (int i = 0; i < 4; ++i)
#pragma unroll
      for (int j = 0; j < 4; ++j)
        acc[i][j] = __builtin_amdgcn_mfma_f32_16x16x32_bf16(af[i], bfr[j], acc[i][j], 0, 0, 0);
    __syncthreads();
  }

  const int rbase = m0 + wm + (lane >> 4) * 4;
#pragma unroll
  for (int j = 0; j < 4; ++j) {
    const int col = n0 + wn + j * 16 + fr;
    if (col >= 384) continue;
    const float bv = bias[col];
#pragma unroll
    for (int i = 0; i < 4; ++i)
#pragma unroll
      for (int r = 0; r < 4; ++r) {
        const int row = rbase + i * 16 + r;
        float v = acc[i][j][r] + bv;
        if (col < 256) {
          P1[(size_t)row * 256 + col] = f2bf(fmaxf(v, 0.f));
        } else {
          QK[(size_t)row * 128 + (col - 256)] = v;
        }
      }
  }
}

// ---------------------------------------------------------------------------
// Activation conversion.
// ---------------------------------------------------------------------------
__global__ __launch_bounds__(256) void conv_acts(
    const float* __restrict__ inputs, const float* __restrict__ hidden,
    short* __restrict__ xin, short* __restrict__ hid) {
  const int NX = ROWS * 352;
  int idx = blockIdx.x * 256 + threadIdx.x;
  if (idx < NX) {
    int row = idx / 352, c = idx - row * 352;
    xin[idx] = (c < 322) ? f2bf(inputs[row * 322 + c]) : (short)0;
  } else {
    int j = idx - NX;
    if (j < ROWS * 256) hid[j] = f2bf(hidden[j]);
  }
}

// ---------------------------------------------------------------------------
// Weight conversion / packing.
// ---------------------------------------------------------------------------
__global__ __launch_bounds__(256) void conv_w(
    const float* __restrict__ W1, const float* __restrict__ Wih,
    const float* __restrict__ Whh, const float* __restrict__ Wp1,
    const float* __restrict__ Wp2, const float* __restrict__ Wq,
    const float* __restrict__ Wk, const float* __restrict__ Wg1,
    const float* __restrict__ Wd1, const float* __restrict__ Wg2,
    const float* __restrict__ Wd2, const float* __restrict__ bp1,
    const float* __restrict__ bq, const float* __restrict__ bg1,
    const float* __restrict__ bd1, const float* __restrict__ bg2,
    const float* __restrict__ bd2,
    short* __restrict__ w1w, short* __restrict__ wihw, short* __restrict__ whhw,
    short* __restrict__ wp2w, short* __restrict__ wpqk, short* __restrict__ wgdw,
    short* __restrict__ wfw, float* __restrict__ bpqkb, float* __restrict__ bgd,
    float* __restrict__ bf2v) {
  int idx = blockIdx.x * 256 + threadIdx.x;
  if (idx < 90112) {
    int r = idx / 352, c = idx - r * 352;
    w1w[idx] = (c < 322) ? f2bf(W1[r * 322 + c]) : (short)0;
    return;
  }
  idx -= 90112;
  if (idx < 196608) { wihw[idx] = f2bf(Wih[idx]); return; }
  idx -= 196608;
  if (idx < 196608) { whhw[idx] = f2bf(Whh[idx]); return; }
  idx -= 196608;
  if (idx < 32768) {
    wp2w[idx] = (idx < 33 * 256) ? f2bf(Wp2[idx]) : (short)0;
    return;
  }
  idx -= 32768;
  if (idx < 131072) {           // WPQK 512x256: [Wp1; Wq; Wk_h; 0]
    int r = idx >> 8, c = idx & 255;
    short v = 0;
    if (r < 256) v = f2bf(Wp1[r * 256 + c]);
    else if (r < 320) v = f2bf(Wq[(r - 256) * 256 + c]);
    else if (r < 384) v = f2bf(Wk[(size_t)(r - 320) * 261 + c]);
    wpqk[idx] = v;
    return;
  }
  idx -= 131072;
  if (idx < 147456) {           // [Wg1 ; Wd1] : 512x288
    wgdw[idx] = (idx < 73728) ? f2bf(Wg1[idx]) : f2bf(Wd1[idx - 73728]);
    return;
  }
  idx -= 147456;
  if (idx < 65536) {            // WFW 128x512: r0 = [Wg2|0]; r1..27 = [0|Wd2]
    int r = idx >> 9, c = idx & 511;
    short v = 0;
    if (r == 0 && c < 256) v = f2bf(Wg2[c]);
    else if (r >= 1 && r < 28 && c >= 256) v = f2bf(Wd2[(r - 1) * 256 + (c - 256)]);
    wfw[idx] = v;
    return;
  }
  idx -= 65536;
  if (idx < 384) {
    bpqkb[idx] = (idx < 256) ? bp1[idx] : ((idx < 320) ? bq[idx - 256] : 0.f);
    return;
  }
  idx -= 384;
  if (idx < 512) { bgd[idx] = (idx < 256) ? bg1[idx] : bd1[idx - 256]; return; }
  idx -= 512;
  if (idx < 128)
    bf2v[idx] = (idx == 0) ? bg2[0] : ((idx < 28) ? bd2[idx - 1] : 0.f);
}

// ---------------------------------------------------------------------------
// GRU elementwise.
// ---------------------------------------------------------------------------
__global__ __launch_bounds__(256) void gru_kernel(
    const short* __restrict__ GI, const short* __restrict__ GH,
    const float* __restrict__ Hin, float* __restrict__ H,
    short* __restrict__ FUS) {
  int idx = blockIdx.x * 256 + threadIdx.x;
  int row = idx >> 6;
  int c = (idx & 63) * 4;
  const short4v gr = *(const short4v*)(GI + (size_t)row * 768 + c);
  const short4v gz = *(const short4v*)(GI + (size_t)row * 768 + 256 + c);
  const short4v gn = *(const short4v*)(GI + (size_t)row * 768 + 512 + c);
  const short4v hr = *(const short4v*)(GH + (size_t)row * 768 + c);
  const short4v hz = *(const short4v*)(GH + (size_t)row * 768 + 256 + c);
  const short4v hn = *(const short4v*)(GH + (size_t)row * 768 + 512 + c);
  const f32x4 hi = *(const f32x4*)(Hin + (size_t)row * 256 + c);
  f32x4 o;
  short4v ob;
#pragma unroll
  for (int p = 0; p < 4; ++p) {
    float r = sigmoidf_(bf2f(gr[p]) + bf2f(hr[p]));
    float z = sigmoidf_(bf2f(gz[p]) + bf2f(hz[p]));
    float n = tanhf(bf2f(gn[p]) + r * bf2f(hn[p]));
    float h = (1.f - z) * n + z * hi[p];
    o[p] = h;
    ob[p] = f2bf(h);
  }
  *(f32x4*)(H + (size_t)row * 256 + c) = o;
  *(short4v*)(FUS + (size_t)row * 288 + c) = ob;
}

// ---------------------------------------------------------------------------
// Per-row softmax over attack logits -> value_source -> sender_values (32).
// ---------------------------------------------------------------------------
__global__ __launch_bounds__(256) void sv_kernel(
    const float* __restrict__ logits, const float* __restrict__ Wv,
    const float* __restrict__ bv, float* __restrict__ SV) {
  const int wave = threadIdx.x >> 6;
  const int lane = threadIdx.x & 63;
  const int row = blockIdx.x * 4 + wave;
  __shared__ float vs_s[4][29];
  float v = (lane < 27) ? logits[(size_t)row * 33 + 6 + lane] : -INFINITY;
  float m = v;
#pragma unroll
  for (int off = 32; off; off >>= 1) m = fmaxf(m, __shfl_xor(m, off));
  float e = (lane < 27) ? __expf(v - m) : 0.f;
  float s = e;
#pragma unroll
  for (int off = 32; off; off >>= 1) s += __shfl_xor(s, off);
  if (lane < 27) vs_s[wave][lane] = e / s;
  if (lane == 27) vs_s[wave][27] = 1.f;
  if (lane == 28) vs_s[wave][28] = 1.f / s;   // top1 = max prob
  __syncthreads();
  if (lane < 32) {
    float acc = bv[lane];
    const float* w = Wv + lane * 29;
#pragma unroll
    for (int c = 0; c < 29; ++c) acc += w[c] * vs_s[wave][c];
    SV[(size_t)row * 32 + lane] = acc;
  }
}

// ---------------------------------------------------------------------------
// Attention v3 (fixed staging): one WAVE per (b,i); grid (1024, 7).
// ALL staging loops are 256-thread-safe (bug in r4-r6: ranges over t>=256
// never ran -> uninitialized LDS, NaN in r6).
// kh staged d-major stride 29 -> score loop 2 lanes/bank (free).
// ---------------------------------------------------------------------------
__global__ __launch_bounds__(256) void attn2_kernel(
    const float* __restrict__ QK, const float* __restrict__ rel,
    const float* __restrict__ Wk, const float* __restrict__ bk,
    const float* __restrict__ SV, const float* __restrict__ null_key,
    const float* __restrict__ null_value, const float* __restrict__ ln_g,
    const float* __restrict__ ln_b, short* __restrict__ FUS) {
  const int b  = blockIdx.x;
  const int iq = blockIdx.y;
  const int t = threadIdx.x;
  const int wave = t >> 6, lane = t & 63;
  const int i = iq * 4 + wave;          // 0..27 (27 invalid)
  const int iw = (i < 27) ? i : 26;     // clamped for safe reads

  __shared__ float kh_s[64 * 29];       // [d-major][j], stride 29
  __shared__ float sv_s[27 * 32];
  __shared__ float q_s[4][64];
  __shared__ float wkr_s[320];
  __shared__ float bk_s[64], nk_s[64];
  __shared__ float nv_s[32], lng_s[32], lnb_s[32];
  __shared__ float rel_s[4][136];
  __shared__ float qws[4][28];          // [0:20) qwkr h*5+r | [20:24) qbk | [24:28) qnull
  __shared__ float s_row[4][112];

  // ---- block stage (all loops safe for blockDim=256) ----
  for (int idx = t; idx < 27 * 64; idx += 256) {
    int r = idx >> 6, c = idx & 63;     // r = j, c = d-index
    kh_s[c * 29 + r] = QK[(size_t)(b * 27 + r) * 128 + 64 + c];
  }
  for (int idx = t; idx < 27 * 32; idx += 256)
    sv_s[idx] = SV[(size_t)b * 864 + idx];
  q_s[wave][lane] = QK[(size_t)(b * 27 + iw) * 128 + lane];
  for (int idx = t; idx < 320; idx += 256) {
    int a = idx / 5, r = idx - a * 5;
    wkr_s[idx] = Wk[(size_t)a * 261 + 256 + r];
  }
  if (t < 64) bk_s[t] = bk[t];
  else if (t < 128) nk_s[t - 64] = null_key[t - 64];
  else if (t < 160) nv_s[t - 128] = null_value[t - 128];
  else if (t < 192) { lng_s[t - 160] = ln_g[t - 160]; lnb_s[t - 160] = ln_b[t - 160]; }
  for (int idx = lane; idx < 135; idx += 64)
    rel_s[wave][idx] = rel[(size_t)(b * 27 + iw) * 135 + idx];
  __syncthreads();

  // ---- per-wave precompute: qwkr, qbk, qnull ----
  if (lane < 28) {
    float acc = 0.f;
    if (lane < 20) {
      const int h = lane / 5, r = lane - h * 5;
#pragma unroll
      for (int d = 0; d < 16; ++d)
        acc += q_s[wave][h * 16 + d] * wkr_s[(h * 16 + d) * 5 + r];
    } else if (lane < 24) {
      const int h = lane - 20;
#pragma unroll
      for (int d = 0; d < 16; ++d)
        acc += q_s[wave][h * 16 + d] * bk_s[h * 16 + d];
    } else {
      const int h = lane - 24;
#pragma unroll
      for (int d = 0; d < 16; ++d)
        acc += q_s[wave][h * 16 + d] * nk_s[h * 16 + d];
    }
    qws[wave][lane] = acc;
  }
  __syncthreads();

  // ---- scores: 112 items (28 j x 4 h) per wave, 2 lane-passes ----
#pragma unroll
  for (int pass = 0; pass < 2; ++pass) {
    const int item = pass * 64 + lane;
    if (item < 112) {
      const int j = item >> 2, h = item & 3;
      float s;
      if (j < 27) {
        float acc = qws[wave][20 + h];
        const float* q  = &q_s[wave][h * 16];
        const float* kh = &kh_s[(h * 16) * 29 + j];
#pragma unroll
        for (int d = 0; d < 16; ++d) acc += q[d] * kh[d * 29];
        const float* rp = &rel_s[wave][j * 5];
        const float* qw = &qws[wave][h * 5];
#pragma unroll
        for (int r = 0; r < 5; ++r) acc += rp[r] * qw[r];
        s = acc * 0.25f;
        if (j == i) s = NEGV;
      } else {
        s = qws[wave][24 + h] * 0.25f;
      }
      s_row[wave][item] = s;
    }
  }
  __syncthreads();

  // ---- top4 + masked softmax over 28 per (i,h): lanes 0..3 ----
  if (lane < 4) {
    float* sp = &s_row[wave][lane];
    float t0 = -INFINITY, t1 = -INFINITY, t2 = -INFINITY, t3 = -INFINITY;
    for (int j = 0; j < 28; ++j) {
      float v = sp[j * 4];
      if (v > t0)      { t3 = t2; t2 = t1; t1 = t0; t0 = v; }
      else if (v > t1) { t3 = t2; t2 = t1; t1 = v; }
      else if (v > t2) { t3 = t2; t2 = v; }
      else if (v > t3) { t3 = v; }
    }
    float sum = 0.f;
    for (int j = 0; j < 28; ++j) {
      float v = sp[j * 4];
      float e = (v >= t3) ? __expf(v - t0) : 0.f;
      sp[j * 4] = e; sum += e;
    }
    const float inv = 1.f / sum;
    for (int j = 0; j < 28; ++j) sp[j * 4] *= inv;
  }
  __syncthreads();

  // ---- messages + layernorm: lanes 0..31 ----
  if (lane < 32) {
    const int h = lane >> 3;
    const float* al = &s_row[wave][h];
    float acc = al[27 * 4] * nv_s[lane];
    for (int j = 0; j < 27; ++j) acc += al[j * 4] * sv_s[j * 32 + lane];
    float sum = acc;
#pragma unroll
    for (int off = 16; off; off >>= 1) sum += __shfl_xor(sum, off);
    const float mu = sum * (1.f / 32.f);
    float d = acc - mu;
    float sq = d * d;
#pragma unroll
    for (int off = 16; off; off >>= 1) sq += __shfl_xor(sq, off);
    const float rs = rsqrtf(sq * (1.f / 32.f) + 1e-5f);
    const float nv = d * rs * lng_s[lane] + lnb_s[lane];
    if (i < 27)
      FUS[(size_t)(b * 27 + i) * 288 + 256 + lane] = f2bf(nv);
  }
}

// ---------------------------------------------------------------------------
// Final fuse.
// ---------------------------------------------------------------------------
__global__ __launch_bounds__(256) void fuse_kernel(
    const float* __restrict__ GDf, const float* __restrict__ LOG,
    float* __restrict__ out) {
  int idx = blockIdx.x * 256 + threadIdx.x;   // over ROWS*33
  int row = idx / 33, c = idx - row * 33;
  float v = LOG[idx];
  if (c >= 6) {
    float gate = sigmoidf_(GDf[(size_t)row * 28]);
    v += 0.1f * gate * GDf[(size_t)row * 28 + (c - 5)];
  }
  out[idx] = v;
}

// ---------------------------------------------------------------------------
extern "C" void kernel_launch(void* const* d_in, const int* in_sizes, int n_in,
                              void* d_out, int out_size, void* d_ws, size_t ws_size,
                              hipStream_t stream) {
  const float* inputs = (const float*)d_in[0];
  const float* hidden = (const float*)d_in[1];
  const float* rel    = (const float*)d_in[2];
  const float* W1  = (const float*)d_in[3];  const float* b1  = (const float*)d_in[4];
  const float* Wih = (const float*)d_in[5];  const float* bih = (const float*)d_in[6];
  const float* Whh = (const float*)d_in[7];  const float* bhh = (const float*)d_in[8];
  const float* Wp1 = (const float*)d_in[9];  const float* bp1 = (const float*)d_in[10];
  const float* Wp2 = (const float*)d_in[11]; const float* bp2 = (const float*)d_in[12];
  const float* Wq  = (const float*)d_in[13]; const float* bq  = (const float*)d_in[14];
  const float* Wk  = (const float*)d_in[15]; const float* bk  = (const float*)d_in[16];
  const float* Wv  = (const float*)d_in[17]; const float* bv  = (const float*)d_in[18];
  const float* ln_g = (const float*)d_in[19]; const float* ln_b = (const float*)d_in[20];
  const float* Wg1 = (const float*)d_in[21]; const float* bg1 = (const float*)d_in[22];
  const float* Wg2 = (const float*)d_in[23]; const float* bg2 = (const float*)d_in[24];
  const float* Wd1 = (const float*)d_in[25]; const float* bd1 = (const float*)d_in[26];
  const float* Wd2 = (const float*)d_in[27]; const float* bd2 = (const float*)d_in[28];
  const float* null_key   = (const float*)d_in[29];
  const float* null_value = (const float*)d_in[30];

  // ---- workspace layout (time-multiplexed; overlap-audited r7) ----
  char* wsb = (char*)d_ws;
  short* GIB = (short*)(wsb + 0);                    // 27648x768 bf16 (42.5MB)
  short* GDB = (short*)(wsb + 0);                    // 27648x512 bf16 (28.3MB)
  short* XINB = (short*)(wsb + 42467328);            // 27648x352 bf16
  short* GHB  = (short*)(wsb + 42467328);            // 27648x768 bf16 (all of R1)
  float* LOG  = (float*)(wsb + 42467328);            // +0       : 3.65MB
  float* QKB  = (float*)(wsb + 42467328 + 4194304);  // +4MiB    : 14.16MB -> ends +18.35MB
  float* SVB  = (float*)(wsb + 42467328 + 18874368); // +18MiB   : 3.54MB  -> ends +22.4MB
  float* LOGD = (float*)(wsb + 42467328 + 23068672); // +22MiB   : 3.10MB  -> ends +26.2MB
  short* XB   = (short*)(wsb + 84934656);
  short* FUS  = (short*)(wsb + 84934656);
  short* HIDB = (short*)(wsb + 84934656 + 16777216);
  short* P1B  = (short*)(wsb + 84934656 + 16777216);
  // Weights (persistent)
  char* wb = wsb + 115867648;
  short* W1W   = (short*)(wb + 0);        // 256x352
  short* WIHW  = (short*)(wb + 180224);   // 768x256
  short* WHHW  = (short*)(wb + 573440);   // 768x256
  short* WP2W  = (short*)(wb + 966656);   // 128x256
  short* WPQK  = (short*)(wb + 1032192);  // 512x256
  short* WGDW  = (short*)(wb + 1294336);  // 512x288
  short* WFW   = (short*)(wb + 1589248);  // 128x512
  float* BPQKb = (float*)(wb + 1720320);  // 384
  float* BGD   = (float*)(wb + 1721856);  // 512
  float* BF2   = (float*)(wb + 1723904);  // 128

  float* out = (float*)d_out;
  float* H   = out + (size_t)ROWS * 33;   // h output region, fp32

  // 1. bf16 conversions / packing
  conv_acts<<<65664, 256, 0, stream>>>(inputs, hidden, XINB, HIDB);
  conv_w<<<3364, 256, 0, stream>>>(W1, Wih, Whh, Wp1, Wp2, Wq, Wk, Wg1, Wd1,
                                   Wg2, Wd2, bp1, bq, bg1, bd1, bg2, bd2,
                                   W1W, WIHW, WHHW, WP2W, WPQK, WGDW, WFW,
                                   BPQKb, BGD, BF2);
  // 2. X = relu(inputs @ W1^T + b1)
  gemm_mfma<1, 1><<<dim3(216, 2), 256, 0, stream>>>(XINB, 352, W1W, 352, b1, XB, 256, 256, 352);
  // 3. GI = X @ Wih^T + bih
  gemm_mfma<0, 1><<<dim3(216, 6), 256, 0, stream>>>(XB, 256, WIHW, 256, bih, GIB, 768, 768, 256);
  // 4. GH = hidden @ Whh^T + bhh
  gemm_mfma<0, 1><<<dim3(216, 6), 256, 0, stream>>>(HIDB, 256, WHHW, 256, bhh, GHB, 768, 768, 256);
  // 5. GRU -> H (fp32, d_out) + fusion[:,0:256] (bf16)
  gru_kernel<<<6912, 256, 0, stream>>>(GIB, GHB, hidden, H, FUS);
  // 6. [P1 | QK] = h @ [Wp1; Wq; Wk_h]^T + [bp1; bq; 0]
  gemm_pqk<<<dim3(216, 3), 256, 0, stream>>>(FUS, WPQK, BPQKb, P1B, QKB);
  // 7. logits = P1 @ Wp2^T + bp2
  gemm_mfma<0, 0><<<dim3(216, 1), 256, 0, stream>>>(P1B, 256, WP2W, 256, bp2, LOG, 33, 33, 256);
  // 8. sender values
  sv_kernel<<<6912, 256, 0, stream>>>(LOG, Wv, bv, SVB);
  // 9. attention v3 -> fusion[:,256:288]
  attn2_kernel<<<dim3(1024, 7), 256, 0, stream>>>(QKB, rel, Wk, bk, SVB, null_key,
                                                  null_value, ln_g, ln_b, FUS);
  // 10. [G1 | D1] = relu(fusion @ [Wg1; Wd1]^T + [bg1; bd1])
  gemm_mfma<1, 1><<<dim3(216, 4), 256, 0, stream>>>(FUS, 288, WGDW, 288, BGD, GDB, 512, 512, 288);
  // 11. GDf = GD @ WFW^T + [bg2; bd2]
  gemm_mfma<0, 0><<<dim3(216, 1), 256, 0, stream>>>(GDB, 512, WFW, 512, BF2, LOGD, 28, 28, 512);
  // 12. final fuse
  fuse_kernel<<<3564, 256, 0, stream>>>(LOGD, LOG, out);
}